// Round 8
// baseline (414.836 us; speedup 1.0000x reference)
//
#include <hip/hip_runtime.h>
#include <hip/hip_fp16.h>

static constexpr float BN_EPS = 1e-5f;

using half8 = __attribute__((ext_vector_type(8))) _Float16;
using f32x4 = __attribute__((ext_vector_type(4))) float;

__device__ __forceinline__ ushort f2h(float f) {
    return __half_as_ushort(__float2half(f));           // RNE
}
__device__ __forceinline__ float2 h2f2(uint u) {
    __half2 h = *reinterpret_cast<__half2*>(&u);
    return __half22float2(h);
}
__device__ __forceinline__ float h2f1(ushort u) {
    __half h = *reinterpret_cast<__half*>(&u);
    return __half2float(h);
}

// ---------------------------------------------------------------------------
// fp32 -> fp16 bulk convert
// ---------------------------------------------------------------------------
__global__ __launch_bounds__(256) void cvt_f16(
    const float* __restrict__ in, ushort* __restrict__ out, int n4)
{
    int i = blockIdx.x * 256 + threadIdx.x;
    const int stride = gridDim.x * 256;
    for (; i < n4; i += stride) {
        const float4 v = ((const float4*)in)[i];
        ushort4 u;
        u.x = f2h(v.x); u.y = f2h(v.y); u.z = f2h(v.z); u.w = f2h(v.w);
        ((ushort4*)out)[i] = u;
    }
}

// ---------------------------------------------------------------------------
// Combined setup: pack all 5 weights into MFMA fragment order, pad b5,
// zero the stats accumulators. One launch.
// Fragment order: dst[((kc*(M/16)+ct)*64 + lane)*8 + j] =
//   fp16( W[kc*32 + 8*(lane>>4)+j][ct*16 + (lane&15)] )
// ---------------------------------------------------------------------------
__device__ __forceinline__ void pack_store(ushort* dst, int M, int k, int c, float v)
{
    const int kc = k >> 5, kk = k & 31, ct = c >> 4;
    const int lane = (c & 15) | ((kk >> 3) << 4);
    const int j = kk & 7;
    dst[((size_t)(kc * (M / 16) + ct) * 64 + lane) * 8 + j] = f2h(v);
}

__global__ __launch_bounds__(256) void pack_all(
    const float* __restrict__ w1, const float* __restrict__ w2,
    const float* __restrict__ w3, const float* __restrict__ w4,
    const float* __restrict__ w5, const float* __restrict__ b5,
    ushort* __restrict__ Wp, float* __restrict__ b5p, float* __restrict__ sums)
{
    int t = blockIdx.x * 256 + threadIdx.x;
    if (t < 16384) { pack_store(Wp, 128, t / 128, t % 128, w1[t]); return; }
    t -= 16384;
    if (t < 8192) { pack_store(Wp + 16384, 64, t / 64, t % 64, w2[t]); return; }
    t -= 8192;
    if (t < 18432) { pack_store(Wp + 24576, 96, t / 96, t % 96, w3[t]); return; }
    t -= 18432;
    if (t < 9216) { pack_store(Wp + 43008, 96, t / 96, t % 96, w4[t]); return; }
    t -= 9216;
    if (t < 1536) {
        const int k = t / 16, c = t % 16;
        pack_store(Wp + 52224, 16, k, c, (c < 10) ? w5[k * 10 + c] : 0.f);
        return;
    }
    t -= 1536;
    if (t < 16) { b5p[t] = (t < 10) ? b5[t] : 0.f; return; }
    t -= 16;
    if (t < 1280) sums[t] = 0.f;
}

// ---------------------------------------------------------------------------
// CSR build: radix-style two-pass counting sort by dst, no global atomics.
// ---------------------------------------------------------------------------
__device__ inline int wave_incl_scan(int v, int lane)
{
#pragma unroll
    for (int s = 1; s < 64; s <<= 1) {
        const int t = __shfl_up(v, s, 64);
        if (lane >= s) v += t;
    }
    return v;
}

__global__ __launch_bounds__(1024) void scan1(
    const int* __restrict__ cnt, int* __restrict__ off, int* __restrict__ bsum, int n)
{
    __shared__ int wsum[16];
    const int tid = threadIdx.x, lane = tid & 63, wid = tid >> 6;
    const int i = blockIdx.x * 1024 + tid;
    const int v = (i < n) ? cnt[i] : 0;
    const int incl = wave_incl_scan(v, lane);
    if (lane == 63) wsum[wid] = incl;
    __syncthreads();
    if (wid == 0) {
        int wv = (lane < 16) ? wsum[lane] : 0;
        wv = wave_incl_scan(wv, lane);
        if (lane < 16) wsum[lane] = wv;
    }
    __syncthreads();
    const int excl = (wid > 0 ? wsum[wid - 1] : 0) + incl - v;
    if (i < n) off[i] = excl;
    if (tid == 1023) bsum[blockIdx.x] = wsum[15];
}

__global__ __launch_bounds__(64) void scan2(int* __restrict__ bsum, int nb)
{
    const int lane = threadIdx.x;
    int carry = 0;
    for (int base = 0; base < nb; base += 64) {
        const int idx = base + lane;
        const int v = (idx < nb) ? bsum[idx] : 0;
        const int incl = wave_incl_scan(v, lane);
        if (idx < nb) bsum[idx] = carry + incl - v;
        carry += __shfl(incl, 63, 64);
    }
}

__global__ __launch_bounds__(1024) void scan3(
    int* __restrict__ off, const int* __restrict__ bsum, int n)
{
    const int i = blockIdx.x * 1024 + threadIdx.x;
    if (i < n) off[i] += bsum[blockIdx.x];
}

// per-(bucket,block) histogram, bucket-major layout H[b*NBLK + blk]
__global__ __launch_bounds__(256) void hist_blocks(
    const int* __restrict__ dst, int* __restrict__ H, int E, int NB, int NBLK)
{
    __shared__ int h[512];
    for (int i = threadIdx.x; i < NB; i += 256) h[i] = 0;
    __syncthreads();
    const int chunk = (E + NBLK - 1) / NBLK;
    const int beg = blockIdx.x * chunk;
    const int end = min(beg + chunk, E);
    for (int i = beg + threadIdx.x; i < end; i += 256)
        atomicAdd(&h[dst[i] >> 7], 1);
    __syncthreads();
    for (int i = threadIdx.x; i < NB; i += 256)
        H[(size_t)i * NBLK + blockIdx.x] = h[i];
}

// deterministic coarse scatter; payload = {src | (dst&127)<<20, ea-f32-bits}
__global__ __launch_bounds__(256) void scatter_coarse(
    const int* __restrict__ src, const int* __restrict__ dst,
    const float* __restrict__ ea, const int* __restrict__ H,
    int2* __restrict__ tmp, int E, int NB, int NBLK)
{
    __shared__ int h[512];
    for (int i = threadIdx.x; i < NB; i += 256)
        h[i] = H[(size_t)i * NBLK + blockIdx.x];
    __syncthreads();
    const int chunk = (E + NBLK - 1) / NBLK;
    const int beg = blockIdx.x * chunk;
    const int end = min(beg + chunk, E);
    for (int i = beg + threadIdx.x; i < end; i += 256) {
        const int d = dst[i];
        const int pos = atomicAdd(&h[d >> 7], 1);
        tmp[pos] = make_int2(src[i] | ((d & 127) << 20), __float_as_int(ea[i]));
    }
}

// per-bucket fine scatter; derives per-node off; final edge = src | f16(ea)<<16
__global__ __launch_bounds__(256) void fill_fine2(
    const int2* __restrict__ tmp, const int* __restrict__ H,
    int* __restrict__ off, uint* __restrict__ edges, int N, int E, int NBLK)
{
    __shared__ int cnt[128];
    __shared__ int wtot;
    const int b = blockIdx.x;
    const int base = b * 128;
    const int tid = threadIdx.x;
    const int lo = H[(size_t)b * NBLK];
    const int hi = (b + 1 < (int)gridDim.x) ? H[(size_t)(b + 1) * NBLK] : E;
    if (tid < 128) cnt[tid] = 0;
    __syncthreads();
    for (int i = lo + tid; i < hi; i += 256)
        atomicAdd(&cnt[(tmp[i].x >> 20) & 127], 1);
    __syncthreads();
    int excl = 0;
    if (tid < 128) {
        const int v = cnt[tid];
        const int incl = wave_incl_scan(v, tid & 63);
        if (tid == 63) wtot = incl;
        excl = incl - v;
    }
    __syncthreads();
    if (tid >= 64 && tid < 128) excl += wtot;
    if (tid < 128) {
        const int o = lo + excl;
        if (base + tid < N) off[base + tid] = o;
        cnt[tid] = o;                         // reuse as heads
    }
    if (b == 0 && tid == 0) off[N] = E;
    __syncthreads();
    for (int i = lo + tid; i < hi; i += 256) {
        const int2 p = tmp[i];
        const int dl = (p.x >> 20) & 127;
        const int pos = atomicAdd(&cnt[dl], 1);
        edges[pos] = (uint)(p.x & 0xFFFF) | ((uint)f2h(__int_as_float(p.y)) << 16);
    }
}

// ---------------------------------------------------------------------------
// GINE aggregation (CSR): 32 lanes/node (4 cols/lane), depth-2 pipelined
// gather, fp16 in/out, optional inline BN affine on input rows.
// outh[node] = fp16( bn(xh[node]) + sum_p relu(bn(xh[src_p]) + a_p*lw + lb) )
// ---------------------------------------------------------------------------
template<bool AFF>
__global__ __launch_bounds__(256) void gine_aggr(
    const ushort* __restrict__ xh, const int* __restrict__ off,
    const uint* __restrict__ edges, const float* __restrict__ lw,
    const float* __restrict__ lb, const float* __restrict__ sc,
    const float* __restrict__ sh, ushort* __restrict__ outh, int N)
{
    const int q = threadIdx.x & 31;                 // column quad: cols 4q..4q+3
    const int node = blockIdx.x * 8 + (threadIdx.x >> 5);
    if (node >= N) return;
    const float4 lw4 = ((const float4*)lw)[q];
    const float4 lb4 = ((const float4*)lb)[q];
    float4 sc4, sh4;
    if constexpr (AFF) {
        sc4 = ((const float4*)sc)[q];
        sh4 = ((const float4*)sh)[q];
    }
    float4 s;
    {
        const uint2 u = ((const uint2*)(xh + (size_t)node * 128))[q];
        float2 f0 = h2f2(u.x), f1 = h2f2(u.y);
        if constexpr (AFF) {
            f0.x = fmaf(f0.x, sc4.x, sh4.x); f0.y = fmaf(f0.y, sc4.y, sh4.y);
            f1.x = fmaf(f1.x, sc4.z, sh4.z); f1.y = fmaf(f1.y, sc4.w, sh4.w);
        }
        s.x = f0.x; s.y = f0.y; s.z = f1.x; s.w = f1.y;
    }
    const int p0 = off[node], pend = off[node + 1];
    uint ecur = 0, enxt = 0;
    uint2 ucur = make_uint2(0, 0), unxt = make_uint2(0, 0);
    if (p0 < pend) {
        ecur = edges[p0];
        ucur = ((const uint2*)(xh + (size_t)(ecur & 0xFFFFu) * 128))[q];
    }
    if (p0 + 1 < pend) {
        enxt = edges[p0 + 1];
        unxt = ((const uint2*)(xh + (size_t)(enxt & 0xFFFFu) * 128))[q];
    }
    for (int pp = p0; pp < pend; ++pp) {
        uint e2 = 0; uint2 u2 = make_uint2(0, 0);
        if (pp + 2 < pend) {
            e2 = edges[pp + 2];
            u2 = ((const uint2*)(xh + (size_t)(e2 & 0xFFFFu) * 128))[q];
        }
        const float a = h2f1((ushort)(ecur >> 16));
        float2 f0 = h2f2(ucur.x), f1 = h2f2(ucur.y);
        if constexpr (AFF) {
            f0.x = fmaf(f0.x, sc4.x, sh4.x); f0.y = fmaf(f0.y, sc4.y, sh4.y);
            f1.x = fmaf(f1.x, sc4.z, sh4.z); f1.y = fmaf(f1.y, sc4.w, sh4.w);
        }
        s.x += fmaxf(fmaf(a, lw4.x, lb4.x) + f0.x, 0.f);
        s.y += fmaxf(fmaf(a, lw4.y, lb4.y) + f0.y, 0.f);
        s.z += fmaxf(fmaf(a, lw4.z, lb4.z) + f1.x, 0.f);
        s.w += fmaxf(fmaf(a, lw4.w, lb4.w) + f1.y, 0.f);
        ecur = enxt; ucur = unxt;
        enxt = e2; unxt = u2;
    }
    ushort4 o;
    o.x = f2h(s.x); o.y = f2h(s.y); o.z = f2h(s.z); o.w = f2h(s.w);
    ((ushort4*)(outh + (size_t)node * 128))[q] = o;
}

// ---------------------------------------------------------------------------
// MFMA fp16 GEMM + bias + relu + BN-stats epilogue + optional per-k input
// affine (BN of the producing layer applied on the fly).
// ---------------------------------------------------------------------------
__device__ __forceinline__ half8 affine_h8(
    half8 a, const float* __restrict__ sc, const float* __restrict__ sh, int k)
{
    const float4 c0 = *(const float4*)(sc + k), c1 = *(const float4*)(sc + k + 4);
    const float4 d0 = *(const float4*)(sh + k), d1 = *(const float4*)(sh + k + 4);
    half8 r;
    r[0] = (_Float16)fmaf((float)a[0], c0.x, d0.x);
    r[1] = (_Float16)fmaf((float)a[1], c0.y, d0.y);
    r[2] = (_Float16)fmaf((float)a[2], c0.z, d0.z);
    r[3] = (_Float16)fmaf((float)a[3], c0.w, d0.w);
    r[4] = (_Float16)fmaf((float)a[4], c1.x, d1.x);
    r[5] = (_Float16)fmaf((float)a[5], c1.y, d1.y);
    r[6] = (_Float16)fmaf((float)a[6], c1.z, d1.z);
    r[7] = (_Float16)fmaf((float)a[7], c1.w, d1.w);
    return r;
}

template<int K, int KS, int M, bool YH, bool AF1, bool AF2>
__global__ __launch_bounds__(256) void gemm_mfma(
    const ushort* __restrict__ A1, const ushort* __restrict__ A2,
    const float* __restrict__ sc1, const float* __restrict__ sh1,
    const float* __restrict__ sc2, const float* __restrict__ sh2,
    const ushort* __restrict__ Wp, const float* __restrict__ bias,
    void* __restrict__ Yv, float* __restrict__ sum, float* __restrict__ sq, int N)
{
    constexpr int NCT = M / 16;
    constexpr int NKC = K / 32;
    __shared__ float redS[4][M];
    __shared__ float redQ[4][M];
    const int tid = threadIdx.x;
    const int w = tid >> 6, l = tid & 63;
    const int col = l & 15, kg = l >> 4;
    const int rowA = blockIdx.x * 64 + w * 16 + col;
    const int rA = (rowA < N) ? rowA : (N - 1);
    f32x4 acc[NCT];
#pragma unroll
    for (int ct = 0; ct < NCT; ++ct) acc[ct] = f32x4{0.f, 0.f, 0.f, 0.f};
#pragma unroll
    for (int kc = 0; kc < NKC; ++kc) {
        const int kbase = kc * 32 + kg * 8;
        half8 a;
        if constexpr (KS < K) {
            if (kbase >= KS) {
                a = *(const half8*)(A2 + (size_t)rA * (K - KS) + (kbase - KS));
                if constexpr (AF2) a = affine_h8(a, sc2, sh2, kbase - KS);
            } else {
                a = *(const half8*)(A1 + (size_t)rA * KS + kbase);
                if constexpr (AF1) a = affine_h8(a, sc1, sh1, kbase);
            }
        } else {
            a = *(const half8*)(A1 + (size_t)rA * K + kbase);
            if constexpr (AF1) a = affine_h8(a, sc1, sh1, kbase);
        }
#pragma unroll
        for (int ct = 0; ct < NCT; ++ct) {
            const half8 wf = *(const half8*)(Wp + ((size_t)(kc * NCT + ct) * 64 + l) * 8);
            acc[ct] = __builtin_amdgcn_mfma_f32_16x16x32_f16(a, wf, acc[ct], 0, 0, 0);
        }
    }
    const int row0 = blockIdx.x * 64 + w * 16 + 4 * kg;
#pragma unroll
    for (int ct = 0; ct < NCT; ++ct) {
        const float bs = bias[ct * 16 + col];
        float sS = 0.f, sQ = 0.f;
#pragma unroll
        for (int r = 0; r < 4; ++r) {
            const int ro = row0 + r;
            if (ro < N) {
                const float o = fmaxf(acc[ct][r] + bs, 0.f);
                if constexpr (YH) ((ushort*)Yv)[(size_t)ro * M + ct * 16 + col] = f2h(o);
                else              ((float*)Yv)[(size_t)ro * M + ct * 16 + col] = o;
                sS += o; sQ = fmaf(o, o, sQ);
            }
        }
        sS += __shfl_xor(sS, 16, 64); sQ += __shfl_xor(sQ, 16, 64);
        sS += __shfl_xor(sS, 32, 64); sQ += __shfl_xor(sQ, 32, 64);
        if (l < 16) { redS[w][ct * 16 + col] = sS; redQ[w][ct * 16 + col] = sQ; }
    }
    __syncthreads();
    for (int i = tid; i < M; i += 256) {
        const float S = redS[0][i] + redS[1][i] + redS[2][i] + redS[3][i];
        const float Q = redQ[0][i] + redQ[1][i] + redQ[2][i] + redQ[3][i];
        unsafeAtomicAdd(&sum[i], S);
        unsafeAtomicAdd(&sq[i], Q);
    }
}

template<int M>
__global__ void bn_finalize(const float* __restrict__ sum, const float* __restrict__ sq,
                            const float* __restrict__ g, const float* __restrict__ be,
                            float* __restrict__ scale, float* __restrict__ shift, float invN)
{
    const int i = threadIdx.x;
    if (i < M) {
        const float m = sum[i] * invN;
        const float v = sq[i] * invN - m * m;
        const float sc = g[i] * rsqrtf(v + BN_EPS);
        scale[i] = sc;
        shift[i] = be[i] - m * sc;
    }
}

__global__ __launch_bounds__(256) void bn_apply_final(
    const float* __restrict__ Y16, const float* __restrict__ scale,
    const float* __restrict__ shift, float* __restrict__ out, int total)
{
    for (int i = blockIdx.x * 256 + threadIdx.x; i < total; i += gridDim.x * 256) {
        const int n = i / 10;
        const int c = i - n * 10;
        out[i] = fmaf(Y16[(size_t)n * 16 + c], scale[c], shift[c]);
    }
}

// ---------------------------------------------------------------------------
extern "C" void kernel_launch(void* const* d_in, const int* in_sizes, int n_in,
                              void* d_out, int out_size, void* d_ws, size_t ws_size,
                              hipStream_t stream)
{
    const float* x   = (const float*)d_in[0];
    const float* ea  = (const float*)d_in[1];
    const int*   ei  = (const int*)d_in[2];
    const float* lw  = (const float*)d_in[3];
    const float* lb  = (const float*)d_in[4];
    const float* w1  = (const float*)d_in[5];
    const float* b1  = (const float*)d_in[6];
    const float* g1  = (const float*)d_in[7];
    const float* be1 = (const float*)d_in[8];
    const float* w2  = (const float*)d_in[9];
    const float* b2  = (const float*)d_in[10];
    const float* g2  = (const float*)d_in[11];
    const float* be2 = (const float*)d_in[12];
    const float* w3  = (const float*)d_in[13];
    const float* b3  = (const float*)d_in[14];
    const float* g3  = (const float*)d_in[15];
    const float* be3 = (const float*)d_in[16];
    const float* w4  = (const float*)d_in[17];
    const float* b4  = (const float*)d_in[18];
    const float* g4  = (const float*)d_in[19];
    const float* be4 = (const float*)d_in[20];
    const float* w5  = (const float*)d_in[21];
    const float* b5  = (const float*)d_in[22];
    const float* g5  = (const float*)d_in[23];
    const float* be5 = (const float*)d_in[24];

    const int N = in_sizes[0] / 128;   // 50000
    const int E = in_sizes[1];         // 1600000
    const int* src = ei;
    const int* dst = ei + E;
    const float invN = 1.0f / (float)N;

    float* ws = (float*)d_ws;
    // fp16 pools (offsets in float units)
    ushort* Pa = (ushort*)ws;                           // N*128 h: xh -> y1h
    ushort* Pb = (ushort*)(ws + (size_t)N * 64);        // N*128 h: t1h -> t2h -> y3h
    ushort* Pc = (ushort*)(ws + (size_t)N * 128);       // N*64 h:  y2h ; later y4h (96) won't fit -> use Pd
    ushort* Pd = (ushort*)(ws + (size_t)N * 160);       // N*96 h:  y4h
    float*  y5 = ws + (size_t)N * 208;                  // N*16 f32
    float*  smallr = ws + (size_t)N * 224;
    float*  sums   = smallr;                            // 10 x 128
    float*  scales = smallr + 1280;                     // 5 x 128
    float*  shifts = smallr + 1920;
    float*  b5p    = smallr + 2560;                     // 16
    ushort* Wp     = (ushort*)(ws + (size_t)N * 224 + 2576);  // 53760 halves
    int*    ibase  = (int*)(ws + (size_t)N * 224 + 2576 + 26880);
    int*    H      = ibase;                             // NB*NBLK (+pad) = 100160
    int*    bsum   = H + 100160;                        // 128
    int2*   tmp    = (int2*)(bsum + 128);               // E int2
    uint*   edges  = (uint*)(tmp + E);                  // E uint
    int*    off    = (int*)(edges + E);                 // N+1
#define SUM(l)   (sums + (l) * 128)
#define SQ(l)    (sums + (5 + (l)) * 128)
#define SCALE(l) (scales + (l) * 128)
#define SHIFT(l) (shifts + (l) * 128)

    pack_all<<<216, 256, 0, stream>>>(w1, w2, w3, w4, w5, b5, Wp, b5p, sums);
    cvt_f16<<<2048, 256, 0, stream>>>(x, Pa, N * 32);   // xh -> Pa

    // ---- CSR build (reused by both convs)
    const int NB   = (N + 127) / 128;                   // 391 coarse buckets
    const int NBLK = 256;
    const int nH   = NB * NBLK;                         // 100096
    const int nbH  = (nH + 1023) / 1024;                // 98
    hist_blocks<<<NBLK, 256, 0, stream>>>(dst, H, E, NB, NBLK);
    scan1<<<nbH, 1024, 0, stream>>>(H, H, bsum, nH);
    scan2<<<1, 64, 0, stream>>>(bsum, nbH);
    scan3<<<nbH, 1024, 0, stream>>>(H, bsum, nH);
    scatter_coarse<<<NBLK, 256, 0, stream>>>(src, dst, ea, H, tmp, E, NB, NBLK);
    fill_fine2<<<NB, 256, 0, stream>>>(tmp, H, off, edges, N, E, NBLK);

    const int gemmGrid = (N + 63) / 64;                 // 782
    const int aggrGrid = (N + 7) / 8;

    // ---- conv1: t1 = x + sum relu(x[src]+e);  y1 = relu(t1@w1+b1) + stats
    gine_aggr<false><<<aggrGrid, 256, 0, stream>>>(
        Pa, off, edges, lw, lb, nullptr, nullptr, Pb, N);                  // t1h -> Pb
    gemm_mfma<128, 128, 128, true, false, false><<<gemmGrid, 256, 0, stream>>>(
        Pb, nullptr, nullptr, nullptr, nullptr, nullptr,
        Wp, b1, Pa, SUM(0), SQ(0), N);                                     // y1h -> Pa
    bn_finalize<128><<<1, 128, 0, stream>>>(SUM(0), SQ(0), g1, be1, SCALE(0), SHIFT(0), invN);

    // ---- conv2: t2 = bn(y1) + sum relu(bn(y1)[src]+e)  (affine inline)
    gine_aggr<true><<<aggrGrid, 256, 0, stream>>>(
        Pa, off, edges, lw, lb, SCALE(0), SHIFT(0), Pb, N);                // t2h -> Pb
    gemm_mfma<128, 128, 64, true, false, false><<<gemmGrid, 256, 0, stream>>>(
        Pb, nullptr, nullptr, nullptr, nullptr, nullptr,
        Wp + 16384, b2, Pc, SUM(1), SQ(1), N);                             // y2h -> Pc
    bn_finalize<64><<<1, 128, 0, stream>>>(SUM(1), SQ(1), g2, be2, SCALE(1), SHIFT(1), invN);

    // ---- lin1: y3 = relu(concat(bn(y1), bn(y2)) @ w3 + b3) (K split 128|64)
    gemm_mfma<192, 128, 96, true, true, true><<<gemmGrid, 256, 0, stream>>>(
        Pa, Pc, SCALE(0), SHIFT(0), SCALE(1), SHIFT(1),
        Wp + 24576, b3, Pb, SUM(2), SQ(2), N);                             // y3h -> Pb
    bn_finalize<96><<<1, 128, 0, stream>>>(SUM(2), SQ(2), g3, be3, SCALE(2), SHIFT(2), invN);

    // ---- mlp1 layer 1: y4 = relu(bn(y3) @ w4 + b4)
    gemm_mfma<96, 96, 96, true, true, false><<<gemmGrid, 256, 0, stream>>>(
        Pb, nullptr, SCALE(2), SHIFT(2), nullptr, nullptr,
        Wp + 43008, b4, Pd, SUM(3), SQ(3), N);                             // y4h -> Pd
    bn_finalize<96><<<1, 128, 0, stream>>>(SUM(3), SQ(3), g4, be4, SCALE(3), SHIFT(3), invN);

    // ---- mlp1 layer 2: y5 = relu(bn(y4) @ w5p + b5p) [N,16] f32
    gemm_mfma<96, 96, 16, false, true, false><<<gemmGrid, 256, 0, stream>>>(
        Pd, nullptr, SCALE(3), SHIFT(3), nullptr, nullptr,
        Wp + 52224, b5p, y5, SUM(4), SQ(4), N);
    bn_finalize<10><<<1, 128, 0, stream>>>(SUM(4), SQ(4), g5, be5, SCALE(4), SHIFT(4), invN);

    // ---- final BN apply -> out [N,10]
    bn_apply_final<<<1024, 256, 0, stream>>>(y5, SCALE(4), SHIFT(4), (float*)d_out, N * 10);
#undef SUM
#undef SQ
#undef SCALE
#undef SHIFT
}

// Round 9
// 350.191 us; speedup vs baseline: 1.1846x; 1.1846x over previous
//
#include <hip/hip_runtime.h>
#include <hip/hip_fp16.h>

static constexpr float BN_EPS = 1e-5f;

using half8 = __attribute__((ext_vector_type(8))) _Float16;
using f32x4 = __attribute__((ext_vector_type(4))) float;

__device__ __forceinline__ ushort f2h(float f) {
    return __half_as_ushort(__float2half(f));           // RNE
}
__device__ __forceinline__ float2 h2f2(uint u) {
    __half2 h = *reinterpret_cast<__half2*>(&u);
    return __half22float2(h);
}
__device__ __forceinline__ float h2f1(ushort u) {
    __half h = *reinterpret_cast<__half*>(&u);
    return __half2float(h);
}

// ---------------------------------------------------------------------------
// fp32 -> fp16 bulk convert
// ---------------------------------------------------------------------------
__global__ __launch_bounds__(256) void cvt_f16(
    const float* __restrict__ in, ushort* __restrict__ out, int n4)
{
    int i = blockIdx.x * 256 + threadIdx.x;
    const int stride = gridDim.x * 256;
    for (; i < n4; i += stride) {
        const float4 v = ((const float4*)in)[i];
        ushort4 u;
        u.x = f2h(v.x); u.y = f2h(v.y); u.z = f2h(v.z); u.w = f2h(v.w);
        ((ushort4*)out)[i] = u;
    }
}

// ---------------------------------------------------------------------------
// Combined setup: pack all 5 weights into MFMA fragment order, pad b5,
// zero the stats accumulators. One launch.
// ---------------------------------------------------------------------------
__device__ __forceinline__ void pack_store(ushort* dst, int M, int k, int c, float v)
{
    const int kc = k >> 5, kk = k & 31, ct = c >> 4;
    const int lane = (c & 15) | ((kk >> 3) << 4);
    const int j = kk & 7;
    dst[((size_t)(kc * (M / 16) + ct) * 64 + lane) * 8 + j] = f2h(v);
}

__global__ __launch_bounds__(256) void pack_all(
    const float* __restrict__ w1, const float* __restrict__ w2,
    const float* __restrict__ w3, const float* __restrict__ w4,
    const float* __restrict__ w5, const float* __restrict__ b5,
    ushort* __restrict__ Wp, float* __restrict__ b5p, float* __restrict__ sums)
{
    int t = blockIdx.x * 256 + threadIdx.x;
    if (t < 16384) { pack_store(Wp, 128, t / 128, t % 128, w1[t]); return; }
    t -= 16384;
    if (t < 8192) { pack_store(Wp + 16384, 64, t / 64, t % 64, w2[t]); return; }
    t -= 8192;
    if (t < 18432) { pack_store(Wp + 24576, 96, t / 96, t % 96, w3[t]); return; }
    t -= 18432;
    if (t < 9216) { pack_store(Wp + 43008, 96, t / 96, t % 96, w4[t]); return; }
    t -= 9216;
    if (t < 1536) {
        const int k = t / 16, c = t % 16;
        pack_store(Wp + 52224, 16, k, c, (c < 10) ? w5[k * 10 + c] : 0.f);
        return;
    }
    t -= 1536;
    if (t < 16) { b5p[t] = (t < 10) ? b5[t] : 0.f; return; }
    t -= 16;
    if (t < 1280) sums[t] = 0.f;
}

// ---------------------------------------------------------------------------
// CSR build: radix-style two-pass counting sort by dst, no global atomics.
// ---------------------------------------------------------------------------
__device__ inline int wave_incl_scan(int v, int lane)
{
#pragma unroll
    for (int s = 1; s < 64; s <<= 1) {
        const int t = __shfl_up(v, s, 64);
        if (lane >= s) v += t;
    }
    return v;
}

__global__ __launch_bounds__(1024) void scan1(
    const int* __restrict__ cnt, int* __restrict__ off, int* __restrict__ bsum, int n)
{
    __shared__ int wsum[16];
    const int tid = threadIdx.x, lane = tid & 63, wid = tid >> 6;
    const int i = blockIdx.x * 1024 + tid;
    const int v = (i < n) ? cnt[i] : 0;
    const int incl = wave_incl_scan(v, lane);
    if (lane == 63) wsum[wid] = incl;
    __syncthreads();
    if (wid == 0) {
        int wv = (lane < 16) ? wsum[lane] : 0;
        wv = wave_incl_scan(wv, lane);
        if (lane < 16) wsum[lane] = wv;
    }
    __syncthreads();
    const int excl = (wid > 0 ? wsum[wid - 1] : 0) + incl - v;
    if (i < n) off[i] = excl;
    if (tid == 1023) bsum[blockIdx.x] = wsum[15];
}

__global__ __launch_bounds__(64) void scan2(int* __restrict__ bsum, int nb)
{
    const int lane = threadIdx.x;
    int carry = 0;
    for (int base = 0; base < nb; base += 64) {
        const int idx = base + lane;
        const int v = (idx < nb) ? bsum[idx] : 0;
        const int incl = wave_incl_scan(v, lane);
        if (idx < nb) bsum[idx] = carry + incl - v;
        carry += __shfl(incl, 63, 64);
    }
}

__global__ __launch_bounds__(1024) void scan3(
    int* __restrict__ off, const int* __restrict__ bsum, int n)
{
    const int i = blockIdx.x * 1024 + threadIdx.x;
    if (i < n) off[i] += bsum[blockIdx.x];
}

// per-(bucket,block) histogram, bucket-major layout H[b*NBLK + blk]
__global__ __launch_bounds__(256) void hist_blocks(
    const int* __restrict__ dst, int* __restrict__ H, int E, int NB, int NBLK)
{
    __shared__ int h[512];
    for (int i = threadIdx.x; i < NB; i += 256) h[i] = 0;
    __syncthreads();
    const int chunk = (E + NBLK - 1) / NBLK;
    const int beg = blockIdx.x * chunk;
    const int end = min(beg + chunk, E);
    for (int i = beg + threadIdx.x; i < end; i += 256)
        atomicAdd(&h[dst[i] >> 7], 1);
    __syncthreads();
    for (int i = threadIdx.x; i < NB; i += 256)
        H[(size_t)i * NBLK + blockIdx.x] = h[i];
}

// deterministic coarse scatter; payload = {src | (dst&127)<<20, ea-f32-bits}
__global__ __launch_bounds__(256) void scatter_coarse(
    const int* __restrict__ src, const int* __restrict__ dst,
    const float* __restrict__ ea, const int* __restrict__ H,
    int2* __restrict__ tmp, int E, int NB, int NBLK)
{
    __shared__ int h[512];
    for (int i = threadIdx.x; i < NB; i += 256)
        h[i] = H[(size_t)i * NBLK + blockIdx.x];
    __syncthreads();
    const int chunk = (E + NBLK - 1) / NBLK;
    const int beg = blockIdx.x * chunk;
    const int end = min(beg + chunk, E);
    for (int i = beg + threadIdx.x; i < end; i += 256) {
        const int d = dst[i];
        const int pos = atomicAdd(&h[d >> 7], 1);
        tmp[pos] = make_int2(src[i] | ((d & 127) << 20), __float_as_int(ea[i]));
    }
}

// per-bucket fine scatter; derives per-node off; final edge = src | f16(ea)<<16
__global__ __launch_bounds__(256) void fill_fine2(
    const int2* __restrict__ tmp, const int* __restrict__ H,
    int* __restrict__ off, uint* __restrict__ edges, int N, int E, int NBLK)
{
    __shared__ int cnt[128];
    __shared__ int wtot;
    const int b = blockIdx.x;
    const int base = b * 128;
    const int tid = threadIdx.x;
    const int lo = H[(size_t)b * NBLK];
    const int hi = (b + 1 < (int)gridDim.x) ? H[(size_t)(b + 1) * NBLK] : E;
    if (tid < 128) cnt[tid] = 0;
    __syncthreads();
    for (int i = lo + tid; i < hi; i += 256)
        atomicAdd(&cnt[(tmp[i].x >> 20) & 127], 1);
    __syncthreads();
    int excl = 0;
    if (tid < 128) {
        const int v = cnt[tid];
        const int incl = wave_incl_scan(v, tid & 63);
        if (tid == 63) wtot = incl;
        excl = incl - v;
    }
    __syncthreads();
    if (tid >= 64 && tid < 128) excl += wtot;
    if (tid < 128) {
        const int o = lo + excl;
        if (base + tid < N) off[base + tid] = o;
        cnt[tid] = o;                         // reuse as heads
    }
    if (b == 0 && tid == 0) off[N] = E;
    __syncthreads();
    for (int i = lo + tid; i < hi; i += 256) {
        const int2 p = tmp[i];
        const int dl = (p.x >> 20) & 127;
        const int pos = atomicAdd(&cnt[dl], 1);
        edges[pos] = (uint)(p.x & 0xFFFF) | ((uint)f2h(__int_as_float(p.y)) << 16);
    }
}

// ---------------------------------------------------------------------------
// GINE aggregation (CSR): 32 lanes/node (4 cols/lane), 8-way branch-free
// edge unroll for memory-level parallelism, fp16 in/out, optional inline BN.
// outh[node] = fp16( bn(xh[node]) + sum_p relu(bn(xh[src_p]) + a_p*lw + lb) )
// ---------------------------------------------------------------------------
template<bool AFF>
__global__ __launch_bounds__(256) void gine_aggr(
    const ushort* __restrict__ xh, const int* __restrict__ off,
    const uint* __restrict__ edges, const float* __restrict__ lw,
    const float* __restrict__ lb, const float* __restrict__ sc,
    const float* __restrict__ sh, ushort* __restrict__ outh, int N)
{
    const int q = threadIdx.x & 31;                 // column quad: cols 4q..4q+3
    const int node = blockIdx.x * 8 + (threadIdx.x >> 5);
    if (node >= N) return;
    const float4 lw4 = ((const float4*)lw)[q];
    const float4 lb4 = ((const float4*)lb)[q];
    float4 sc4, sh4;
    if constexpr (AFF) {
        sc4 = ((const float4*)sc)[q];
        sh4 = ((const float4*)sh)[q];
    }
    float4 s;
    {
        const uint2 u = ((const uint2*)(xh + (size_t)node * 128))[q];
        float2 f0 = h2f2(u.x), f1 = h2f2(u.y);
        if constexpr (AFF) {
            f0.x = fmaf(f0.x, sc4.x, sh4.x); f0.y = fmaf(f0.y, sc4.y, sh4.y);
            f1.x = fmaf(f1.x, sc4.z, sh4.z); f1.y = fmaf(f1.y, sc4.w, sh4.w);
        }
        s.x = f0.x; s.y = f0.y; s.z = f1.x; s.w = f1.y;
    }

    auto acc1 = [&](uint e, uint2 u) {
        const float a = h2f1((ushort)(e >> 16));
        float2 f0 = h2f2(u.x), f1 = h2f2(u.y);
        if constexpr (AFF) {
            f0.x = fmaf(f0.x, sc4.x, sh4.x); f0.y = fmaf(f0.y, sc4.y, sh4.y);
            f1.x = fmaf(f1.x, sc4.z, sh4.z); f1.y = fmaf(f1.y, sc4.w, sh4.w);
        }
        s.x += fmaxf(fmaf(a, lw4.x, lb4.x) + f0.x, 0.f);
        s.y += fmaxf(fmaf(a, lw4.y, lb4.y) + f0.y, 0.f);
        s.z += fmaxf(fmaf(a, lw4.z, lb4.z) + f1.x, 0.f);
        s.w += fmaxf(fmaf(a, lw4.w, lb4.w) + f1.y, 0.f);
    };

    int p = off[node];
    const int pend = off[node + 1];
    // 8-way branch-free main loop: 8 independent row gathers in flight
    for (; p + 8 <= pend; p += 8) {
        const uint e0 = edges[p + 0], e1 = edges[p + 1];
        const uint e2 = edges[p + 2], e3 = edges[p + 3];
        const uint e4 = edges[p + 4], e5 = edges[p + 5];
        const uint e6 = edges[p + 6], e7 = edges[p + 7];
        const uint2 u0 = ((const uint2*)(xh + (size_t)(e0 & 0xFFFFu) * 128))[q];
        const uint2 u1 = ((const uint2*)(xh + (size_t)(e1 & 0xFFFFu) * 128))[q];
        const uint2 u2 = ((const uint2*)(xh + (size_t)(e2 & 0xFFFFu) * 128))[q];
        const uint2 u3 = ((const uint2*)(xh + (size_t)(e3 & 0xFFFFu) * 128))[q];
        const uint2 u4 = ((const uint2*)(xh + (size_t)(e4 & 0xFFFFu) * 128))[q];
        const uint2 u5 = ((const uint2*)(xh + (size_t)(e5 & 0xFFFFu) * 128))[q];
        const uint2 u6 = ((const uint2*)(xh + (size_t)(e6 & 0xFFFFu) * 128))[q];
        const uint2 u7 = ((const uint2*)(xh + (size_t)(e7 & 0xFFFFu) * 128))[q];
        acc1(e0, u0); acc1(e1, u1); acc1(e2, u2); acc1(e3, u3);
        acc1(e4, u4); acc1(e5, u5); acc1(e6, u6); acc1(e7, u7);
    }
    for (; p < pend; ++p) {
        const uint e = edges[p];
        const uint2 u = ((const uint2*)(xh + (size_t)(e & 0xFFFFu) * 128))[q];
        acc1(e, u);
    }
    ushort4 o;
    o.x = f2h(s.x); o.y = f2h(s.y); o.z = f2h(s.z); o.w = f2h(s.w);
    ((ushort4*)(outh + (size_t)node * 128))[q] = o;
}

// ---------------------------------------------------------------------------
// MFMA fp16 GEMM + bias + relu + BN-stats epilogue + optional per-k input
// affine (BN of the producing layer applied on the fly).
// ---------------------------------------------------------------------------
__device__ __forceinline__ half8 affine_h8(
    half8 a, const float* __restrict__ sc, const float* __restrict__ sh, int k)
{
    const float4 c0 = *(const float4*)(sc + k), c1 = *(const float4*)(sc + k + 4);
    const float4 d0 = *(const float4*)(sh + k), d1 = *(const float4*)(sh + k + 4);
    half8 r;
    r[0] = (_Float16)fmaf((float)a[0], c0.x, d0.x);
    r[1] = (_Float16)fmaf((float)a[1], c0.y, d0.y);
    r[2] = (_Float16)fmaf((float)a[2], c0.z, d0.z);
    r[3] = (_Float16)fmaf((float)a[3], c0.w, d0.w);
    r[4] = (_Float16)fmaf((float)a[4], c1.x, d1.x);
    r[5] = (_Float16)fmaf((float)a[5], c1.y, d1.y);
    r[6] = (_Float16)fmaf((float)a[6], c1.z, d1.z);
    r[7] = (_Float16)fmaf((float)a[7], c1.w, d1.w);
    return r;
}

template<int K, int KS, int M, bool YH, bool AF1, bool AF2>
__global__ __launch_bounds__(256) void gemm_mfma(
    const ushort* __restrict__ A1, const ushort* __restrict__ A2,
    const float* __restrict__ sc1, const float* __restrict__ sh1,
    const float* __restrict__ sc2, const float* __restrict__ sh2,
    const ushort* __restrict__ Wp, const float* __restrict__ bias,
    void* __restrict__ Yv, float* __restrict__ sum, float* __restrict__ sq, int N)
{
    constexpr int NCT = M / 16;
    constexpr int NKC = K / 32;
    __shared__ float redS[4][M];
    __shared__ float redQ[4][M];
    const int tid = threadIdx.x;
    const int w = tid >> 6, l = tid & 63;
    const int col = l & 15, kg = l >> 4;
    const int rowA = blockIdx.x * 64 + w * 16 + col;
    const int rA = (rowA < N) ? rowA : (N - 1);
    f32x4 acc[NCT];
#pragma unroll
    for (int ct = 0; ct < NCT; ++ct) acc[ct] = f32x4{0.f, 0.f, 0.f, 0.f};
#pragma unroll
    for (int kc = 0; kc < NKC; ++kc) {
        const int kbase = kc * 32 + kg * 8;
        half8 a;
        if constexpr (KS < K) {
            if (kbase >= KS) {
                a = *(const half8*)(A2 + (size_t)rA * (K - KS) + (kbase - KS));
                if constexpr (AF2) a = affine_h8(a, sc2, sh2, kbase - KS);
            } else {
                a = *(const half8*)(A1 + (size_t)rA * KS + kbase);
                if constexpr (AF1) a = affine_h8(a, sc1, sh1, kbase);
            }
        } else {
            a = *(const half8*)(A1 + (size_t)rA * K + kbase);
            if constexpr (AF1) a = affine_h8(a, sc1, sh1, kbase);
        }
#pragma unroll
        for (int ct = 0; ct < NCT; ++ct) {
            const half8 wf = *(const half8*)(Wp + ((size_t)(kc * NCT + ct) * 64 + l) * 8);
            acc[ct] = __builtin_amdgcn_mfma_f32_16x16x32_f16(a, wf, acc[ct], 0, 0, 0);
        }
    }
    const int row0 = blockIdx.x * 64 + w * 16 + 4 * kg;
#pragma unroll
    for (int ct = 0; ct < NCT; ++ct) {
        const float bs = bias[ct * 16 + col];
        float sS = 0.f, sQ = 0.f;
#pragma unroll
        for (int r = 0; r < 4; ++r) {
            const int ro = row0 + r;
            if (ro < N) {
                const float o = fmaxf(acc[ct][r] + bs, 0.f);
                if constexpr (YH) ((ushort*)Yv)[(size_t)ro * M + ct * 16 + col] = f2h(o);
                else              ((float*)Yv)[(size_t)ro * M + ct * 16 + col] = o;
                sS += o; sQ = fmaf(o, o, sQ);
            }
        }
        sS += __shfl_xor(sS, 16, 64); sQ += __shfl_xor(sQ, 16, 64);
        sS += __shfl_xor(sS, 32, 64); sQ += __shfl_xor(sQ, 32, 64);
        if (l < 16) { redS[w][ct * 16 + col] = sS; redQ[w][ct * 16 + col] = sQ; }
    }
    __syncthreads();
    for (int i = tid; i < M; i += 256) {
        const float S = redS[0][i] + redS[1][i] + redS[2][i] + redS[3][i];
        const float Q = redQ[0][i] + redQ[1][i] + redQ[2][i] + redQ[3][i];
        unsafeAtomicAdd(&sum[i], S);
        unsafeAtomicAdd(&sq[i], Q);
    }
}

template<int M>
__global__ void bn_finalize(const float* __restrict__ sum, const float* __restrict__ sq,
                            const float* __restrict__ g, const float* __restrict__ be,
                            float* __restrict__ scale, float* __restrict__ shift, float invN)
{
    const int i = threadIdx.x;
    if (i < M) {
        const float m = sum[i] * invN;
        const float v = sq[i] * invN - m * m;
        const float sc = g[i] * rsqrtf(v + BN_EPS);
        scale[i] = sc;
        shift[i] = be[i] - m * sc;
    }
}

__global__ __launch_bounds__(256) void bn_apply_final(
    const float* __restrict__ Y16, const float* __restrict__ scale,
    const float* __restrict__ shift, float* __restrict__ out, int total)
{
    for (int i = blockIdx.x * 256 + threadIdx.x; i < total; i += gridDim.x * 256) {
        const int n = i / 10;
        const int c = i - n * 10;
        out[i] = fmaf(Y16[(size_t)n * 16 + c], scale[c], shift[c]);
    }
}

// ---------------------------------------------------------------------------
extern "C" void kernel_launch(void* const* d_in, const int* in_sizes, int n_in,
                              void* d_out, int out_size, void* d_ws, size_t ws_size,
                              hipStream_t stream)
{
    const float* x   = (const float*)d_in[0];
    const float* ea  = (const float*)d_in[1];
    const int*   ei  = (const int*)d_in[2];
    const float* lw  = (const float*)d_in[3];
    const float* lb  = (const float*)d_in[4];
    const float* w1  = (const float*)d_in[5];
    const float* b1  = (const float*)d_in[6];
    const float* g1  = (const float*)d_in[7];
    const float* be1 = (const float*)d_in[8];
    const float* w2  = (const float*)d_in[9];
    const float* b2  = (const float*)d_in[10];
    const float* g2  = (const float*)d_in[11];
    const float* be2 = (const float*)d_in[12];
    const float* w3  = (const float*)d_in[13];
    const float* b3  = (const float*)d_in[14];
    const float* g3  = (const float*)d_in[15];
    const float* be3 = (const float*)d_in[16];
    const float* w4  = (const float*)d_in[17];
    const float* b4  = (const float*)d_in[18];
    const float* g4  = (const float*)d_in[19];
    const float* be4 = (const float*)d_in[20];
    const float* w5  = (const float*)d_in[21];
    const float* b5  = (const float*)d_in[22];
    const float* g5  = (const float*)d_in[23];
    const float* be5 = (const float*)d_in[24];

    const int N = in_sizes[0] / 128;   // 50000
    const int E = in_sizes[1];         // 1600000
    const int* src = ei;
    const int* dst = ei + E;
    const float invN = 1.0f / (float)N;

    float* ws = (float*)d_ws;
    // fp16 pools (offsets in float units)
    ushort* Pa = (ushort*)ws;                           // N*128 h: xh -> y1h
    ushort* Pb = (ushort*)(ws + (size_t)N * 64);        // N*128 h: t1h -> t2h -> y3h
    ushort* Pc = (ushort*)(ws + (size_t)N * 128);       // N*64 h:  y2h
    ushort* Pd = (ushort*)(ws + (size_t)N * 160);       // N*96 h:  y4h
    float*  y5 = ws + (size_t)N * 208;                  // N*16 f32
    float*  smallr = ws + (size_t)N * 224;
    float*  sums   = smallr;                            // 10 x 128
    float*  scales = smallr + 1280;                     // 5 x 128
    float*  shifts = smallr + 1920;
    float*  b5p    = smallr + 2560;                     // 16
    ushort* Wp     = (ushort*)(ws + (size_t)N * 224 + 2576);  // 53760 halves
    int*    ibase  = (int*)(ws + (size_t)N * 224 + 2576 + 26880);
    int*    H      = ibase;                             // NB*NBLK (+pad) = 100160
    int*    bsum   = H + 100160;                        // 128
    int2*   tmp    = (int2*)(bsum + 128);               // E int2
    uint*   edges  = (uint*)(tmp + E);                  // E uint
    int*    off    = (int*)(edges + E);                 // N+1
#define SUM(l)   (sums + (l) * 128)
#define SQ(l)    (sums + (5 + (l)) * 128)
#define SCALE(l) (scales + (l) * 128)
#define SHIFT(l) (shifts + (l) * 128)

    pack_all<<<216, 256, 0, stream>>>(w1, w2, w3, w4, w5, b5, Wp, b5p, sums);
    cvt_f16<<<2048, 256, 0, stream>>>(x, Pa, N * 32);   // xh -> Pa

    // ---- CSR build (reused by both convs)
    const int NB   = (N + 127) / 128;                   // 391 coarse buckets
    const int NBLK = 256;
    const int nH   = NB * NBLK;                         // 100096
    const int nbH  = (nH + 1023) / 1024;                // 98
    hist_blocks<<<NBLK, 256, 0, stream>>>(dst, H, E, NB, NBLK);
    scan1<<<nbH, 1024, 0, stream>>>(H, H, bsum, nH);
    scan2<<<1, 64, 0, stream>>>(bsum, nbH);
    scan3<<<nbH, 1024, 0, stream>>>(H, bsum, nH);
    scatter_coarse<<<NBLK, 256, 0, stream>>>(src, dst, ea, H, tmp, E, NB, NBLK);
    fill_fine2<<<NB, 256, 0, stream>>>(tmp, H, off, edges, N, E, NBLK);

    const int gemmGrid = (N + 63) / 64;                 // 782
    const int aggrGrid = (N + 7) / 8;

    // ---- conv1: t1 = x + sum relu(x[src]+e);  y1 = relu(t1@w1+b1) + stats
    gine_aggr<false><<<aggrGrid, 256, 0, stream>>>(
        Pa, off, edges, lw, lb, nullptr, nullptr, Pb, N);                  // t1h -> Pb
    gemm_mfma<128, 128, 128, true, false, false><<<gemmGrid, 256, 0, stream>>>(
        Pb, nullptr, nullptr, nullptr, nullptr, nullptr,
        Wp, b1, Pa, SUM(0), SQ(0), N);                                     // y1h -> Pa
    bn_finalize<128><<<1, 128, 0, stream>>>(SUM(0), SQ(0), g1, be1, SCALE(0), SHIFT(0), invN);

    // ---- conv2: t2 = bn(y1) + sum relu(bn(y1)[src]+e)  (affine inline)
    gine_aggr<true><<<aggrGrid, 256, 0, stream>>>(
        Pa, off, edges, lw, lb, SCALE(0), SHIFT(0), Pb, N);                // t2h -> Pb
    gemm_mfma<128, 128, 64, true, false, false><<<gemmGrid, 256, 0, stream>>>(
        Pb, nullptr, nullptr, nullptr, nullptr, nullptr,
        Wp + 16384, b2, Pc, SUM(1), SQ(1), N);                             // y2h -> Pc
    bn_finalize<64><<<1, 128, 0, stream>>>(SUM(1), SQ(1), g2, be2, SCALE(1), SHIFT(1), invN);

    // ---- lin1: y3 = relu(concat(bn(y1), bn(y2)) @ w3 + b3) (K split 128|64)
    gemm_mfma<192, 128, 96, true, true, true><<<gemmGrid, 256, 0, stream>>>(
        Pa, Pc, SCALE(0), SHIFT(0), SCALE(1), SHIFT(1),
        Wp + 24576, b3, Pb, SUM(2), SQ(2), N);                             // y3h -> Pb
    bn_finalize<96><<<1, 128, 0, stream>>>(SUM(2), SQ(2), g3, be3, SCALE(2), SHIFT(2), invN);

    // ---- mlp1 layer 1: y4 = relu(bn(y3) @ w4 + b4)
    gemm_mfma<96, 96, 96, true, true, false><<<gemmGrid, 256, 0, stream>>>(
        Pb, nullptr, SCALE(2), SHIFT(2), nullptr, nullptr,
        Wp + 43008, b4, Pd, SUM(3), SQ(3), N);                             // y4h -> Pd
    bn_finalize<96><<<1, 128, 0, stream>>>(SUM(3), SQ(3), g4, be4, SCALE(3), SHIFT(3), invN);

    // ---- mlp1 layer 2: y5 = relu(bn(y4) @ w5p + b5p) [N,16] f32
    gemm_mfma<96, 96, 16, false, true, false><<<gemmGrid, 256, 0, stream>>>(
        Pd, nullptr, SCALE(3), SHIFT(3), nullptr, nullptr,
        Wp + 52224, b5p, y5, SUM(4), SQ(4), N);
    bn_finalize<10><<<1, 128, 0, stream>>>(SUM(4), SQ(4), g5, be5, SCALE(4), SHIFT(4), invN);

    // ---- final BN apply -> out [N,10]
    bn_apply_final<<<1024, 256, 0, stream>>>(y5, SCALE(4), SHIFT(4), (float*)d_out, N * 10);
#undef SUM
#undef SQ
#undef SCALE
#undef SHIFT
}

// Round 10
// 332.228 us; speedup vs baseline: 1.2486x; 1.0541x over previous
//
#include <hip/hip_runtime.h>
#include <hip/hip_fp16.h>

static constexpr float BN_EPS = 1e-5f;

using half8 = __attribute__((ext_vector_type(8))) _Float16;
using f32x4 = __attribute__((ext_vector_type(4))) float;

__device__ __forceinline__ ushort f2h(float f) {
    return __half_as_ushort(__float2half(f));           // RNE
}
__device__ __forceinline__ float2 h2f2(uint u) {
    __half2 h = *reinterpret_cast<__half2*>(&u);
    return __half22float2(h);
}
__device__ __forceinline__ float h2f1(ushort u) {
    __half h = *reinterpret_cast<__half*>(&u);
    return __half2float(h);
}

// ---------------------------------------------------------------------------
// fp32 -> fp16 bulk convert
// ---------------------------------------------------------------------------
__global__ __launch_bounds__(256) void cvt_f16(
    const float* __restrict__ in, ushort* __restrict__ out, int n4)
{
    int i = blockIdx.x * 256 + threadIdx.x;
    const int stride = gridDim.x * 256;
    for (; i < n4; i += stride) {
        const float4 v = ((const float4*)in)[i];
        ushort4 u;
        u.x = f2h(v.x); u.y = f2h(v.y); u.z = f2h(v.z); u.w = f2h(v.w);
        ((ushort4*)out)[i] = u;
    }
}

// ---------------------------------------------------------------------------
// Combined setup: pack all 5 weights into MFMA fragment order, pad b5,
// zero the stats accumulators. One launch.
// ---------------------------------------------------------------------------
__device__ __forceinline__ void pack_store(ushort* dst, int M, int k, int c, float v)
{
    const int kc = k >> 5, kk = k & 31, ct = c >> 4;
    const int lane = (c & 15) | ((kk >> 3) << 4);
    const int j = kk & 7;
    dst[((size_t)(kc * (M / 16) + ct) * 64 + lane) * 8 + j] = f2h(v);
}

__global__ __launch_bounds__(256) void pack_all(
    const float* __restrict__ w1, const float* __restrict__ w2,
    const float* __restrict__ w3, const float* __restrict__ w4,
    const float* __restrict__ w5, const float* __restrict__ b5,
    ushort* __restrict__ Wp, float* __restrict__ b5p, float* __restrict__ sums)
{
    int t = blockIdx.x * 256 + threadIdx.x;
    if (t < 16384) { pack_store(Wp, 128, t / 128, t % 128, w1[t]); return; }
    t -= 16384;
    if (t < 8192) { pack_store(Wp + 16384, 64, t / 64, t % 64, w2[t]); return; }
    t -= 8192;
    if (t < 18432) { pack_store(Wp + 24576, 96, t / 96, t % 96, w3[t]); return; }
    t -= 18432;
    if (t < 9216) { pack_store(Wp + 43008, 96, t / 96, t % 96, w4[t]); return; }
    t -= 9216;
    if (t < 1536) {
        const int k = t / 16, c = t % 16;
        pack_store(Wp + 52224, 16, k, c, (c < 10) ? w5[k * 10 + c] : 0.f);
        return;
    }
    t -= 1536;
    if (t < 16) { b5p[t] = (t < 10) ? b5[t] : 0.f; return; }
    t -= 16;
    if (t < 1280) sums[t] = 0.f;
}

// ---------------------------------------------------------------------------
// CSR build: radix-style two-pass counting sort by dst, no global atomics.
// ---------------------------------------------------------------------------
__device__ inline int wave_incl_scan(int v, int lane)
{
#pragma unroll
    for (int s = 1; s < 64; s <<= 1) {
        const int t = __shfl_up(v, s, 64);
        if (lane >= s) v += t;
    }
    return v;
}

__global__ __launch_bounds__(1024) void scan1(
    const int* __restrict__ cnt, int* __restrict__ off, int* __restrict__ bsum, int n)
{
    __shared__ int wsum[16];
    const int tid = threadIdx.x, lane = tid & 63, wid = tid >> 6;
    const int i = blockIdx.x * 1024 + tid;
    const int v = (i < n) ? cnt[i] : 0;
    const int incl = wave_incl_scan(v, lane);
    if (lane == 63) wsum[wid] = incl;
    __syncthreads();
    if (wid == 0) {
        int wv = (lane < 16) ? wsum[lane] : 0;
        wv = wave_incl_scan(wv, lane);
        if (lane < 16) wsum[lane] = wv;
    }
    __syncthreads();
    const int excl = (wid > 0 ? wsum[wid - 1] : 0) + incl - v;
    if (i < n) off[i] = excl;
    if (tid == 1023) bsum[blockIdx.x] = wsum[15];
}

__global__ __launch_bounds__(64) void scan2(int* __restrict__ bsum, int nb)
{
    const int lane = threadIdx.x;
    int carry = 0;
    for (int base = 0; base < nb; base += 64) {
        const int idx = base + lane;
        const int v = (idx < nb) ? bsum[idx] : 0;
        const int incl = wave_incl_scan(v, lane);
        if (idx < nb) bsum[idx] = carry + incl - v;
        carry += __shfl(incl, 63, 64);
    }
}

__global__ __launch_bounds__(1024) void scan3(
    int* __restrict__ off, const int* __restrict__ bsum, int n)
{
    const int i = blockIdx.x * 1024 + threadIdx.x;
    if (i < n) off[i] += bsum[blockIdx.x];
}

// per-(bucket,block) histogram, bucket-major layout H[b*NBLK + blk]
__global__ __launch_bounds__(256) void hist_blocks(
    const int* __restrict__ dst, int* __restrict__ H, int E, int NB, int NBLK)
{
    __shared__ int h[512];
    for (int i = threadIdx.x; i < NB; i += 256) h[i] = 0;
    __syncthreads();
    const int chunk = (E + NBLK - 1) / NBLK;
    const int beg = blockIdx.x * chunk;
    const int end = min(beg + chunk, E);
    for (int i = beg + threadIdx.x; i < end; i += 256)
        atomicAdd(&h[dst[i] >> 7], 1);
    __syncthreads();
    for (int i = threadIdx.x; i < NB; i += 256)
        H[(size_t)i * NBLK + blockIdx.x] = h[i];
}

// deterministic coarse scatter; payload = {src | (dst&127)<<20, ea-f32-bits}
__global__ __launch_bounds__(256) void scatter_coarse(
    const int* __restrict__ src, const int* __restrict__ dst,
    const float* __restrict__ ea, const int* __restrict__ H,
    int2* __restrict__ tmp, int E, int NB, int NBLK)
{
    __shared__ int h[512];
    for (int i = threadIdx.x; i < NB; i += 256)
        h[i] = H[(size_t)i * NBLK + blockIdx.x];
    __syncthreads();
    const int chunk = (E + NBLK - 1) / NBLK;
    const int beg = blockIdx.x * chunk;
    const int end = min(beg + chunk, E);
    for (int i = beg + threadIdx.x; i < end; i += 256) {
        const int d = dst[i];
        const int pos = atomicAdd(&h[d >> 7], 1);
        tmp[pos] = make_int2(src[i] | ((d & 127) << 20), __float_as_int(ea[i]));
    }
}

// per-bucket fine scatter; derives per-node off; final edge = src | f16(ea)<<16
__global__ __launch_bounds__(256) void fill_fine2(
    const int2* __restrict__ tmp, const int* __restrict__ H,
    int* __restrict__ off, uint* __restrict__ edges, int N, int E, int NBLK)
{
    __shared__ int cnt[128];
    __shared__ int wtot;
    const int b = blockIdx.x;
    const int base = b * 128;
    const int tid = threadIdx.x;
    const int lo = H[(size_t)b * NBLK];
    const int hi = (b + 1 < (int)gridDim.x) ? H[(size_t)(b + 1) * NBLK] : E;
    if (tid < 128) cnt[tid] = 0;
    __syncthreads();
    for (int i = lo + tid; i < hi; i += 256)
        atomicAdd(&cnt[(tmp[i].x >> 20) & 127], 1);
    __syncthreads();
    int excl = 0;
    if (tid < 128) {
        const int v = cnt[tid];
        const int incl = wave_incl_scan(v, tid & 63);
        if (tid == 63) wtot = incl;
        excl = incl - v;
    }
    __syncthreads();
    if (tid >= 64 && tid < 128) excl += wtot;
    if (tid < 128) {
        const int o = lo + excl;
        if (base + tid < N) off[base + tid] = o;
        cnt[tid] = o;                         // reuse as heads
    }
    if (b == 0 && tid == 0) off[N] = E;
    __syncthreads();
    for (int i = lo + tid; i < hi; i += 256) {
        const int2 p = tmp[i];
        const int dl = (p.x >> 20) & 127;
        const int pos = atomicAdd(&cnt[dl], 1);
        edges[pos] = (uint)(p.x & 0xFFFF) | ((uint)f2h(__int_as_float(p.y)) << 16);
    }
}

// ---------------------------------------------------------------------------
// GINE aggregation (CSR): 32 lanes/node (4 cols/lane), 1-ahead rotating
// software pipeline (measured-best structure), fp16 in/out.
// AFF: BN scale/shift computed in-register from raw sum/sumsq stats.
// outh[node] = fp16( bn(xh[node]) + sum_p relu(bn(xh[src_p]) + a_p*lw + lb) )
// ---------------------------------------------------------------------------
template<bool AFF>
__global__ __launch_bounds__(256) void gine_aggr(
    const ushort* __restrict__ xh, const int* __restrict__ off,
    const uint* __restrict__ edges, const float* __restrict__ lw,
    const float* __restrict__ lb, const float* __restrict__ su,
    const float* __restrict__ qu, const float* __restrict__ g,
    const float* __restrict__ be, float invN,
    ushort* __restrict__ outh, int N)
{
    const int q = threadIdx.x & 31;                 // column quad: cols 4q..4q+3
    const int node = blockIdx.x * 8 + (threadIdx.x >> 5);
    if (node >= N) return;
    const float4 lw4 = ((const float4*)lw)[q];
    const float4 lb4 = ((const float4*)lb)[q];
    float4 sc4, sh4;
    if constexpr (AFF) {
        const float4 sv = ((const float4*)su)[q];
        const float4 qv = ((const float4*)qu)[q];
        const float4 gv = ((const float4*)g)[q];
        const float4 bv = ((const float4*)be)[q];
        float4 m;
        m.x = sv.x * invN; m.y = sv.y * invN; m.z = sv.z * invN; m.w = sv.w * invN;
        sc4.x = gv.x * rsqrtf(qv.x * invN - m.x * m.x + BN_EPS);
        sc4.y = gv.y * rsqrtf(qv.y * invN - m.y * m.y + BN_EPS);
        sc4.z = gv.z * rsqrtf(qv.z * invN - m.z * m.z + BN_EPS);
        sc4.w = gv.w * rsqrtf(qv.w * invN - m.w * m.w + BN_EPS);
        sh4.x = bv.x - m.x * sc4.x; sh4.y = bv.y - m.y * sc4.y;
        sh4.z = bv.z - m.z * sc4.z; sh4.w = bv.w - m.w * sc4.w;
    }
    float4 s;
    {
        const uint2 u = ((const uint2*)(xh + (size_t)node * 128))[q];
        float2 f0 = h2f2(u.x), f1 = h2f2(u.y);
        if constexpr (AFF) {
            f0.x = fmaf(f0.x, sc4.x, sh4.x); f0.y = fmaf(f0.y, sc4.y, sh4.y);
            f1.x = fmaf(f1.x, sc4.z, sh4.z); f1.y = fmaf(f1.y, sc4.w, sh4.w);
        }
        s.x = f0.x; s.y = f0.y; s.z = f1.x; s.w = f1.y;
    }
    int p = off[node];
    const int pend = off[node + 1];
    if (p < pend) {
        uint e = edges[p];
        uint2 u = ((const uint2*)(xh + (size_t)(e & 0xFFFFu) * 128))[q];
        for (++p; p < pend; ++p) {
            const uint en = edges[p];
            const uint2 un = ((const uint2*)(xh + (size_t)(en & 0xFFFFu) * 128))[q];
            const float a = h2f1((ushort)(e >> 16));
            float2 f0 = h2f2(u.x), f1 = h2f2(u.y);
            if constexpr (AFF) {
                f0.x = fmaf(f0.x, sc4.x, sh4.x); f0.y = fmaf(f0.y, sc4.y, sh4.y);
                f1.x = fmaf(f1.x, sc4.z, sh4.z); f1.y = fmaf(f1.y, sc4.w, sh4.w);
            }
            s.x += fmaxf(fmaf(a, lw4.x, lb4.x) + f0.x, 0.f);
            s.y += fmaxf(fmaf(a, lw4.y, lb4.y) + f0.y, 0.f);
            s.z += fmaxf(fmaf(a, lw4.z, lb4.z) + f1.x, 0.f);
            s.w += fmaxf(fmaf(a, lw4.w, lb4.w) + f1.y, 0.f);
            e = en; u = un;
        }
        const float a = h2f1((ushort)(e >> 16));
        float2 f0 = h2f2(u.x), f1 = h2f2(u.y);
        if constexpr (AFF) {
            f0.x = fmaf(f0.x, sc4.x, sh4.x); f0.y = fmaf(f0.y, sc4.y, sh4.y);
            f1.x = fmaf(f1.x, sc4.z, sh4.z); f1.y = fmaf(f1.y, sc4.w, sh4.w);
        }
        s.x += fmaxf(fmaf(a, lw4.x, lb4.x) + f0.x, 0.f);
        s.y += fmaxf(fmaf(a, lw4.y, lb4.y) + f0.y, 0.f);
        s.z += fmaxf(fmaf(a, lw4.z, lb4.z) + f1.x, 0.f);
        s.w += fmaxf(fmaf(a, lw4.w, lb4.w) + f1.y, 0.f);
    }
    ushort4 o;
    o.x = f2h(s.x); o.y = f2h(s.y); o.z = f2h(s.z); o.w = f2h(s.w);
    ((ushort4*)(outh + (size_t)node * 128))[q] = o;
}

// ---------------------------------------------------------------------------
// MFMA fp16 GEMM + bias + relu + BN-stats epilogue + optional per-k input
// affine. Affine scale/shift computed in an LDS prologue from raw stats.
// ---------------------------------------------------------------------------
__device__ __forceinline__ half8 affine_h8(
    half8 a, const float* sc, const float* sh, int k)
{
    const float4 c0 = *(const float4*)(sc + k), c1 = *(const float4*)(sc + k + 4);
    const float4 d0 = *(const float4*)(sh + k), d1 = *(const float4*)(sh + k + 4);
    half8 r;
    r[0] = (_Float16)fmaf((float)a[0], c0.x, d0.x);
    r[1] = (_Float16)fmaf((float)a[1], c0.y, d0.y);
    r[2] = (_Float16)fmaf((float)a[2], c0.z, d0.z);
    r[3] = (_Float16)fmaf((float)a[3], c0.w, d0.w);
    r[4] = (_Float16)fmaf((float)a[4], c1.x, d1.x);
    r[5] = (_Float16)fmaf((float)a[5], c1.y, d1.y);
    r[6] = (_Float16)fmaf((float)a[6], c1.z, d1.z);
    r[7] = (_Float16)fmaf((float)a[7], c1.w, d1.w);
    return r;
}

template<int K, int KS, int M, bool YH, bool AF1, bool AF2>
__global__ __launch_bounds__(256) void gemm_mfma(
    const ushort* __restrict__ A1, const ushort* __restrict__ A2,
    const float* __restrict__ su1, const float* __restrict__ sq1_,
    const float* __restrict__ g1, const float* __restrict__ be1,
    const float* __restrict__ su2, const float* __restrict__ sq2_,
    const float* __restrict__ g2, const float* __restrict__ be2,
    const ushort* __restrict__ Wp, const float* __restrict__ bias,
    void* __restrict__ Yv, float* __restrict__ sum, float* __restrict__ sq,
    int N, float invN)
{
    constexpr int NCT = M / 16;
    constexpr int NKC = K / 32;
    __shared__ float redS[4][M];
    __shared__ float redQ[4][M];
    __shared__ float scL[K];
    __shared__ float shL[K];
    const int tid = threadIdx.x;
    if constexpr (AF1 || AF2) {
        for (int i = tid; i < K; i += 256) {
            float s_, q_, g_, b_;
            if (i < KS) { s_ = su1[i]; q_ = sq1_[i]; g_ = g1[i]; b_ = be1[i]; }
            else        { s_ = su2[i - KS]; q_ = sq2_[i - KS]; g_ = g2[i - KS]; b_ = be2[i - KS]; }
            const float m = s_ * invN;
            const float c = g_ * rsqrtf(q_ * invN - m * m + BN_EPS);
            scL[i] = c; shL[i] = b_ - m * c;
        }
        __syncthreads();
    }
    const int w = tid >> 6, l = tid & 63;
    const int col = l & 15, kg = l >> 4;
    const int rowA = blockIdx.x * 64 + w * 16 + col;
    const int rA = (rowA < N) ? rowA : (N - 1);
    f32x4 acc[NCT];
#pragma unroll
    for (int ct = 0; ct < NCT; ++ct) acc[ct] = f32x4{0.f, 0.f, 0.f, 0.f};
#pragma unroll
    for (int kc = 0; kc < NKC; ++kc) {
        const int kbase = kc * 32 + kg * 8;
        half8 a;
        if constexpr (KS < K) {
            if (kbase >= KS) {
                a = *(const half8*)(A2 + (size_t)rA * (K - KS) + (kbase - KS));
                if constexpr (AF2) a = affine_h8(a, scL, shL, kbase);
            } else {
                a = *(const half8*)(A1 + (size_t)rA * KS + kbase);
                if constexpr (AF1) a = affine_h8(a, scL, shL, kbase);
            }
        } else {
            a = *(const half8*)(A1 + (size_t)rA * K + kbase);
            if constexpr (AF1) a = affine_h8(a, scL, shL, kbase);
        }
#pragma unroll
        for (int ct = 0; ct < NCT; ++ct) {
            const half8 wf = *(const half8*)(Wp + ((size_t)(kc * NCT + ct) * 64 + l) * 8);
            acc[ct] = __builtin_amdgcn_mfma_f32_16x16x32_f16(a, wf, acc[ct], 0, 0, 0);
        }
    }
    const int row0 = blockIdx.x * 64 + w * 16 + 4 * kg;
#pragma unroll
    for (int ct = 0; ct < NCT; ++ct) {
        const float bs = bias[ct * 16 + col];
        float sS = 0.f, sQ = 0.f;
#pragma unroll
        for (int r = 0; r < 4; ++r) {
            const int ro = row0 + r;
            if (ro < N) {
                const float o = fmaxf(acc[ct][r] + bs, 0.f);
                if constexpr (YH) ((ushort*)Yv)[(size_t)ro * M + ct * 16 + col] = f2h(o);
                else              ((float*)Yv)[(size_t)ro * M + ct * 16 + col] = o;
                sS += o; sQ = fmaf(o, o, sQ);
            }
        }
        sS += __shfl_xor(sS, 16, 64); sQ += __shfl_xor(sQ, 16, 64);
        sS += __shfl_xor(sS, 32, 64); sQ += __shfl_xor(sQ, 32, 64);
        if (l < 16) { redS[w][ct * 16 + col] = sS; redQ[w][ct * 16 + col] = sQ; }
    }
    __syncthreads();
    for (int i = tid; i < M; i += 256) {
        const float S = redS[0][i] + redS[1][i] + redS[2][i] + redS[3][i];
        const float Q = redQ[0][i] + redQ[1][i] + redQ[2][i] + redQ[3][i];
        unsafeAtomicAdd(&sum[i], S);
        unsafeAtomicAdd(&sq[i], Q);
    }
}

// final BN apply (scale/shift computed inline from raw stats) -> out [N,10]
__global__ __launch_bounds__(256) void bn_apply_final(
    const float* __restrict__ Y16, const float* __restrict__ su,
    const float* __restrict__ qu, const float* __restrict__ g5,
    const float* __restrict__ be5, float* __restrict__ out, int total, float invN)
{
    for (int i = blockIdx.x * 256 + threadIdx.x; i < total; i += gridDim.x * 256) {
        const int n = i / 10;
        const int c = i - n * 10;
        const float m = su[c] * invN;
        const float sc = g5[c] * rsqrtf(qu[c] * invN - m * m + BN_EPS);
        const float sh = be5[c] - m * sc;
        out[i] = fmaf(Y16[(size_t)n * 16 + c], sc, sh);
    }
}

// ---------------------------------------------------------------------------
extern "C" void kernel_launch(void* const* d_in, const int* in_sizes, int n_in,
                              void* d_out, int out_size, void* d_ws, size_t ws_size,
                              hipStream_t stream)
{
    const float* x   = (const float*)d_in[0];
    const float* ea  = (const float*)d_in[1];
    const int*   ei  = (const int*)d_in[2];
    const float* lw  = (const float*)d_in[3];
    const float* lb  = (const float*)d_in[4];
    const float* w1  = (const float*)d_in[5];
    const float* b1  = (const float*)d_in[6];
    const float* g1  = (const float*)d_in[7];
    const float* be1 = (const float*)d_in[8];
    const float* w2  = (const float*)d_in[9];
    const float* b2  = (const float*)d_in[10];
    const float* g2  = (const float*)d_in[11];
    const float* be2 = (const float*)d_in[12];
    const float* w3  = (const float*)d_in[13];
    const float* b3  = (const float*)d_in[14];
    const float* g3  = (const float*)d_in[15];
    const float* be3 = (const float*)d_in[16];
    const float* w4  = (const float*)d_in[17];
    const float* b4  = (const float*)d_in[18];
    const float* g4  = (const float*)d_in[19];
    const float* be4 = (const float*)d_in[20];
    const float* w5  = (const float*)d_in[21];
    const float* b5  = (const float*)d_in[22];
    const float* g5  = (const float*)d_in[23];
    const float* be5 = (const float*)d_in[24];

    const int N = in_sizes[0] / 128;   // 50000
    const int E = in_sizes[1];         // 1600000
    const int* src = ei;
    const int* dst = ei + E;
    const float invN = 1.0f / (float)N;

    float* ws = (float*)d_ws;
    // fp16 pools (offsets in float units)
    ushort* Pa = (ushort*)ws;                           // N*128 h: xh -> y1h
    ushort* Pb = (ushort*)(ws + (size_t)N * 64);        // N*128 h: t1h -> t2h -> y3h
    ushort* Pc = (ushort*)(ws + (size_t)N * 128);       // N*64 h:  y2h
    ushort* Pd = (ushort*)(ws + (size_t)N * 160);       // N*96 h:  y4h
    float*  y5 = ws + (size_t)N * 208;                  // N*16 f32
    float*  smallr = ws + (size_t)N * 224;
    float*  sums   = smallr;                            // 10 x 128
    float*  b5p    = smallr + 1280;                     // 16
    ushort* Wp     = (ushort*)(ws + (size_t)N * 224 + 1296);  // 53760 halves
    int*    ibase  = (int*)(ws + (size_t)N * 224 + 1296 + 26880);
    int*    H      = ibase;                             // NB*NBLK (+pad) = 100160
    int*    bsum   = H + 100160;                        // 128
    int2*   tmp    = (int2*)(bsum + 128);               // E int2
    uint*   edges  = (uint*)(tmp + E);                  // E uint
    int*    off    = (int*)(edges + E);                 // N+1
#define SUM(l)   (sums + (l) * 128)
#define SQ(l)    (sums + (5 + (l)) * 128)

    pack_all<<<216, 256, 0, stream>>>(w1, w2, w3, w4, w5, b5, Wp, b5p, sums);
    cvt_f16<<<2048, 256, 0, stream>>>(x, Pa, N * 32);   // xh -> Pa

    // ---- CSR build (reused by both convs)
    const int NB   = (N + 127) / 128;                   // 391 coarse buckets
    const int NBLK = 256;
    const int nH   = NB * NBLK;                         // 100096
    const int nbH  = (nH + 1023) / 1024;                // 98
    hist_blocks<<<NBLK, 256, 0, stream>>>(dst, H, E, NB, NBLK);
    scan1<<<nbH, 1024, 0, stream>>>(H, H, bsum, nH);
    scan2<<<1, 64, 0, stream>>>(bsum, nbH);
    scan3<<<nbH, 1024, 0, stream>>>(H, bsum, nH);
    scatter_coarse<<<NBLK, 256, 0, stream>>>(src, dst, ea, H, tmp, E, NB, NBLK);
    fill_fine2<<<NB, 256, 0, stream>>>(tmp, H, off, edges, N, E, NBLK);

    const int gemmGrid = (N + 63) / 64;                 // 782
    const int aggrGrid = (N + 7) / 8;

    // ---- conv1: t1 = x + sum relu(x[src]+e);  y1 = relu(t1@w1+b1) + stats
    gine_aggr<false><<<aggrGrid, 256, 0, stream>>>(
        Pa, off, edges, lw, lb, nullptr, nullptr, nullptr, nullptr, invN, Pb, N);
    gemm_mfma<128, 128, 128, true, false, false><<<gemmGrid, 256, 0, stream>>>(
        Pb, nullptr, nullptr, nullptr, nullptr, nullptr,
        nullptr, nullptr, nullptr, nullptr,
        Wp, b1, Pa, SUM(0), SQ(0), N, invN);                               // y1h -> Pa

    // ---- conv2: t2 = bn(y1) + sum relu(bn(y1)[src]+e)  (affine from stats)
    gine_aggr<true><<<aggrGrid, 256, 0, stream>>>(
        Pa, off, edges, lw, lb, SUM(0), SQ(0), g1, be1, invN, Pb, N);      // t2h -> Pb
    gemm_mfma<128, 128, 64, true, false, false><<<gemmGrid, 256, 0, stream>>>(
        Pb, nullptr, nullptr, nullptr, nullptr, nullptr,
        nullptr, nullptr, nullptr, nullptr,
        Wp + 16384, b2, Pc, SUM(1), SQ(1), N, invN);                       // y2h -> Pc

    // ---- lin1: y3 = relu(concat(bn(y1), bn(y2)) @ w3 + b3) (K split 128|64)
    gemm_mfma<192, 128, 96, true, true, true><<<gemmGrid, 256, 0, stream>>>(
        Pa, Pc, SUM(0), SQ(0), g1, be1, SUM(1), SQ(1), g2, be2,
        Wp + 24576, b3, Pb, SUM(2), SQ(2), N, invN);                       // y3h -> Pb

    // ---- mlp1 layer 1: y4 = relu(bn(y3) @ w4 + b4)
    gemm_mfma<96, 96, 96, true, true, false><<<gemmGrid, 256, 0, stream>>>(
        Pb, nullptr, SUM(2), SQ(2), g3, be3, nullptr, nullptr, nullptr, nullptr,
        Wp + 43008, b4, Pd, SUM(3), SQ(3), N, invN);                       // y4h -> Pd

    // ---- mlp1 layer 2: y5 = relu(bn(y4) @ w5p + b5p) [N,16] f32
    gemm_mfma<96, 96, 16, false, true, false><<<gemmGrid, 256, 0, stream>>>(
        Pd, nullptr, SUM(3), SQ(3), g4, be4, nullptr, nullptr, nullptr, nullptr,
        Wp + 52224, b5p, y5, SUM(4), SQ(4), N, invN);

    // ---- final BN apply -> out [N,10]
    bn_apply_final<<<1024, 256, 0, stream>>>(y5, SUM(4), SQ(4), g5, be5,
                                             (float*)d_out, N * 10, invN);
#undef SUM
#undef SQ
}

// Round 12
// 326.570 us; speedup vs baseline: 1.2703x; 1.0173x over previous
//
#include <hip/hip_runtime.h>
#include <hip/hip_fp16.h>

static constexpr float BN_EPS = 1e-5f;

using half8 = __attribute__((ext_vector_type(8))) _Float16;
using f32x4 = __attribute__((ext_vector_type(4))) float;

__device__ __forceinline__ ushort f2h(float f) {
    return __half_as_ushort(__float2half(f));           // RNE
}
__device__ __forceinline__ __half2 u2h2(uint u) {
    union { uint u; __half2 h; } c; c.u = u; return c.h;
}
__device__ __forceinline__ uint h22u(__half2 h) {
    union { uint u; __half2 h; } c; c.h = h; return c.u;
}
__device__ __forceinline__ uint pk2(float a, float b) {
    return (uint)f2h(a) | ((uint)f2h(b) << 16);
}
// packed relu on a half2 word: zero any half with sign bit set
__device__ __forceinline__ uint relu2u(uint u) {
    return u & ~(((u >> 15) & 0x10001u) * 0xFFFFu);
}

// ---------------------------------------------------------------------------
// fp32 -> fp16 bulk convert
// ---------------------------------------------------------------------------
__global__ __launch_bounds__(256) void cvt_f16(
    const float* __restrict__ in, ushort* __restrict__ out, int n4)
{
    int i = blockIdx.x * 256 + threadIdx.x;
    const int stride = gridDim.x * 256;
    for (; i < n4; i += stride) {
        const float4 v = ((const float4*)in)[i];
        ushort4 u;
        u.x = f2h(v.x); u.y = f2h(v.y); u.z = f2h(v.z); u.w = f2h(v.w);
        ((ushort4*)out)[i] = u;
    }
}

// ---------------------------------------------------------------------------
// Combined setup: pack 5 weights to MFMA fragment order, pad b5, zero stats,
// pack lw/lb to half2. One launch.
// ---------------------------------------------------------------------------
__device__ __forceinline__ void pack_store(ushort* dst, int M, int k, int c, float v)
{
    const int kc = k >> 5, kk = k & 31, ct = c >> 4;
    const int lane = (c & 15) | ((kk >> 3) << 4);
    const int j = kk & 7;
    dst[((size_t)(kc * (M / 16) + ct) * 64 + lane) * 8 + j] = f2h(v);
}

__global__ __launch_bounds__(256) void pack_all(
    const float* __restrict__ w1, const float* __restrict__ w2,
    const float* __restrict__ w3, const float* __restrict__ w4,
    const float* __restrict__ w5, const float* __restrict__ b5,
    const float* __restrict__ lw, const float* __restrict__ lb,
    ushort* __restrict__ Wp, float* __restrict__ b5p, float* __restrict__ sums,
    uint* __restrict__ lwh, uint* __restrict__ lbh)
{
    int t = blockIdx.x * 256 + threadIdx.x;
    if (t < 16384) { pack_store(Wp, 128, t / 128, t % 128, w1[t]); return; }
    t -= 16384;
    if (t < 8192) { pack_store(Wp + 16384, 64, t / 64, t % 64, w2[t]); return; }
    t -= 8192;
    if (t < 18432) { pack_store(Wp + 24576, 96, t / 96, t % 96, w3[t]); return; }
    t -= 18432;
    if (t < 9216) { pack_store(Wp + 43008, 96, t / 96, t % 96, w4[t]); return; }
    t -= 9216;
    if (t < 1536) {
        const int k = t / 16, c = t % 16;
        pack_store(Wp + 52224, 16, k, c, (c < 10) ? w5[k * 10 + c] : 0.f);
        return;
    }
    t -= 1536;
    if (t < 16) { b5p[t] = (t < 10) ? b5[t] : 0.f; return; }
    t -= 16;
    if (t < 1280) { sums[t] = 0.f; return; }
    t -= 1280;
    if (t < 64) { lwh[t] = pk2(lw[2 * t], lw[2 * t + 1]); return; }
    t -= 64;
    if (t < 64) { lbh[t] = pk2(lb[2 * t], lb[2 * t + 1]); return; }
}

// ---------------------------------------------------------------------------
// CSR build: radix-style two-pass counting sort by dst, no global atomics.
// ---------------------------------------------------------------------------
__device__ inline int wave_incl_scan(int v, int lane)
{
#pragma unroll
    for (int s = 1; s < 64; s <<= 1) {
        const int t = __shfl_up(v, s, 64);
        if (lane >= s) v += t;
    }
    return v;
}

__global__ __launch_bounds__(1024) void scan1(
    const int* __restrict__ cnt, int* __restrict__ off, int* __restrict__ bsum, int n)
{
    __shared__ int wsum[16];
    const int tid = threadIdx.x, lane = tid & 63, wid = tid >> 6;
    const int i = blockIdx.x * 1024 + tid;
    const int v = (i < n) ? cnt[i] : 0;
    const int incl = wave_incl_scan(v, lane);
    if (lane == 63) wsum[wid] = incl;
    __syncthreads();
    if (wid == 0) {
        int wv = (lane < 16) ? wsum[lane] : 0;
        wv = wave_incl_scan(wv, lane);
        if (lane < 16) wsum[lane] = wv;
    }
    __syncthreads();
    const int excl = (wid > 0 ? wsum[wid - 1] : 0) + incl - v;
    if (i < n) off[i] = excl;
    if (tid == 1023) bsum[blockIdx.x] = wsum[15];
}

__global__ __launch_bounds__(64) void scan2(int* __restrict__ bsum, int nb)
{
    const int lane = threadIdx.x;
    int carry = 0;
    for (int base = 0; base < nb; base += 64) {
        const int idx = base + lane;
        const int v = (idx < nb) ? bsum[idx] : 0;
        const int incl = wave_incl_scan(v, lane);
        if (idx < nb) bsum[idx] = carry + incl - v;
        carry += __shfl(incl, 63, 64);
    }
}

__global__ __launch_bounds__(1024) void scan3(
    int* __restrict__ off, const int* __restrict__ bsum, int n)
{
    const int i = blockIdx.x * 1024 + threadIdx.x;
    if (i < n) off[i] += bsum[blockIdx.x];
}

// per-(bucket,block) histogram, bucket-major layout H[b*NBLK + blk]
__global__ __launch_bounds__(256) void hist_blocks(
    const int* __restrict__ dst, int* __restrict__ H, int E, int NB, int NBLK)
{
    __shared__ int h[512];
    for (int i = threadIdx.x; i < NB; i += 256) h[i] = 0;
    __syncthreads();
    const int chunk = (E + NBLK - 1) / NBLK;
    const int beg = blockIdx.x * chunk;
    const int end = min(beg + chunk, E);
    for (int i = beg + threadIdx.x; i < end; i += 256)
        atomicAdd(&h[dst[i] >> 7], 1);
    __syncthreads();
    for (int i = threadIdx.x; i < NB; i += 256)
        H[(size_t)i * NBLK + blockIdx.x] = h[i];
}

// deterministic coarse scatter; tmp_e = src|f16(ea)<<16 (final edge payload),
// tmp_d = dst&127 (fine bucket key)
__global__ __launch_bounds__(256) void scatter_coarse(
    const int* __restrict__ src, const int* __restrict__ dst,
    const float* __restrict__ ea, const int* __restrict__ H,
    uint* __restrict__ tmp_e, uchar* __restrict__ tmp_d, int E, int NB, int NBLK)
{
    __shared__ int h[512];
    for (int i = threadIdx.x; i < NB; i += 256)
        h[i] = H[(size_t)i * NBLK + blockIdx.x];
    __syncthreads();
    const int chunk = (E + NBLK - 1) / NBLK;
    const int beg = blockIdx.x * chunk;
    const int end = min(beg + chunk, E);
    for (int i = beg + threadIdx.x; i < end; i += 256) {
        const int d = dst[i];
        const int pos = atomicAdd(&h[d >> 7], 1);
        tmp_e[pos] = (uint)(src[i] & 0xFFFF) | ((uint)f2h(ea[i]) << 16);
        tmp_d[pos] = (uchar)(d & 127);
    }
}

// per-bucket fine scatter; derives per-node off; edges[pos] = tmp_e[i]
__global__ __launch_bounds__(256) void fill_fine2(
    const uint* __restrict__ tmp_e, const uchar* __restrict__ tmp_d,
    const int* __restrict__ H, int* __restrict__ off, uint* __restrict__ edges,
    int N, int E, int NBLK)
{
    __shared__ int cnt[128];
    __shared__ int wtot;
    const int b = blockIdx.x;
    const int base = b * 128;
    const int tid = threadIdx.x;
    const int lo = H[(size_t)b * NBLK];
    const int hi = (b + 1 < (int)gridDim.x) ? H[(size_t)(b + 1) * NBLK] : E;
    if (tid < 128) cnt[tid] = 0;
    __syncthreads();
    for (int i = lo + tid; i < hi; i += 256)
        atomicAdd(&cnt[tmp_d[i]], 1);
    __syncthreads();
    int excl = 0;
    if (tid < 128) {
        const int v = cnt[tid];
        const int incl = wave_incl_scan(v, tid & 63);
        if (tid == 63) wtot = incl;
        excl = incl - v;
    }
    __syncthreads();
    if (tid >= 64 && tid < 128) excl += wtot;
    if (tid < 128) {
        const int o = lo + excl;
        if (base + tid < N) off[base + tid] = o;
        cnt[tid] = o;                         // reuse as heads
    }
    if (b == 0 && tid == 0) off[N] = E;
    __syncthreads();
    for (int i = lo + tid; i < hi; i += 256) {
        const int dl = tmp_d[i];
        const uint pe = tmp_e[i];
        const int pos = atomicAdd(&cnt[dl], 1);
        edges[pos] = pe;
    }
}

// ---------------------------------------------------------------------------
// GINE aggregation (CSR): 16 lanes/node (8 cols/lane, uint4 gather), 4 nodes
// per wave, 1-ahead rotation, PACKED fp16 math (v_pk_fma/add_f16 + bit-relu),
// fp16 accumulators. AFF: BN scale/shift from raw stats, packed to half2.
// outh[node] = fp16( bn(xh[node]) + sum_p relu(bn(xh[src_p]) + a_p*lw + lb) )
// ---------------------------------------------------------------------------
template<bool AFF>
__global__ __launch_bounds__(256) void gine_aggr(
    const ushort* __restrict__ xh, const int* __restrict__ off,
    const uint* __restrict__ edges, const uint* __restrict__ lwh,
    const uint* __restrict__ lbh, const float* __restrict__ su,
    const float* __restrict__ qu, const float* __restrict__ g,
    const float* __restrict__ be, float invN,
    ushort* __restrict__ outh, int N)
{
    const int q = threadIdx.x & 15;                 // cols 8q .. 8q+7
    const int node = blockIdx.x * 16 + (threadIdx.x >> 4);
    if (node >= N) return;
    __half2 lw[4], lb[4], sc[4], sh[4];
#pragma unroll
    for (int i = 0; i < 4; ++i) {
        lw[i] = u2h2(lwh[q * 4 + i]);
        lb[i] = u2h2(lbh[q * 4 + i]);
    }
    if constexpr (AFF) {
        const int c0 = q * 8;
#pragma unroll
        for (int i = 0; i < 4; ++i) {
            const float2 s2 = *(const float2*)(su + c0 + 2 * i);
            const float2 q2 = *(const float2*)(qu + c0 + 2 * i);
            const float2 g2 = *(const float2*)(g + c0 + 2 * i);
            const float2 b2 = *(const float2*)(be + c0 + 2 * i);
            const float m0 = s2.x * invN, m1 = s2.y * invN;
            const float c0f = g2.x * rsqrtf(q2.x * invN - m0 * m0 + BN_EPS);
            const float c1f = g2.y * rsqrtf(q2.y * invN - m1 * m1 + BN_EPS);
            sc[i] = u2h2(pk2(c0f, c1f));
            sh[i] = u2h2(pk2(b2.x - m0 * c0f, b2.y - m1 * c1f));
        }
    }
    __half2 acc[4];
    {
        const uint4 u = ((const uint4*)(xh + (size_t)node * 128))[q];
        acc[0] = u2h2(u.x); acc[1] = u2h2(u.y); acc[2] = u2h2(u.z); acc[3] = u2h2(u.w);
        if constexpr (AFF) {
#pragma unroll
            for (int i = 0; i < 4; ++i) acc[i] = __hfma2(acc[i], sc[i], sh[i]);
        }
    }

    auto proc = [&](uint e, uint4 u) {
        const __half2 a2 = u2h2((e >> 16) * 0x10001u);
        uint ua[4] = {u.x, u.y, u.z, u.w};
#pragma unroll
        for (int i = 0; i < 4; ++i) {
            __half2 x2 = u2h2(ua[i]);
            if constexpr (AFF) x2 = __hfma2(x2, sc[i], sh[i]);
            __half2 m = __hfma2(a2, lw[i], lb[i]);
            m = __hadd2(x2, m);
            m = u2h2(relu2u(h22u(m)));           // packed relu (bit trick)
            acc[i] = __hadd2(acc[i], m);
        }
    };

    int p = off[node];
    const int pend = off[node + 1];
    if (p < pend) {
        uint e = edges[p];
        uint4 u = ((const uint4*)(xh + (size_t)(e & 0xFFFFu) * 128))[q];
        for (++p; p < pend; ++p) {
            const uint en = edges[p];
            const uint4 un = ((const uint4*)(xh + (size_t)(en & 0xFFFFu) * 128))[q];
            proc(e, u);
            e = en; u = un;
        }
        proc(e, u);
    }
    uint4 o;
    o.x = h22u(acc[0]); o.y = h22u(acc[1]); o.z = h22u(acc[2]); o.w = h22u(acc[3]);
    ((uint4*)(outh + (size_t)node * 128))[q] = o;
}

// ---------------------------------------------------------------------------
// MFMA fp16 GEMM + bias + relu + BN-stats epilogue + optional per-k input
// affine. Affine scale/shift computed in an LDS prologue from raw stats.
// ---------------------------------------------------------------------------
__device__ __forceinline__ half8 affine_h8(
    half8 a, const float* sc, const float* sh, int k)
{
    const float4 c0 = *(const float4*)(sc + k), c1 = *(const float4*)(sc + k + 4);
    const float4 d0 = *(const float4*)(sh + k), d1 = *(const float4*)(sh + k + 4);
    half8 r;
    r[0] = (_Float16)fmaf((float)a[0], c0.x, d0.x);
    r[1] = (_Float16)fmaf((float)a[1], c0.y, d0.y);
    r[2] = (_Float16)fmaf((float)a[2], c0.z, d0.z);
    r[3] = (_Float16)fmaf((float)a[3], c0.w, d0.w);
    r[4] = (_Float16)fmaf((float)a[4], c1.x, d1.x);
    r[5] = (_Float16)fmaf((float)a[5], c1.y, d1.y);
    r[6] = (_Float16)fmaf((float)a[6], c1.z, d1.z);
    r[7] = (_Float16)fmaf((float)a[7], c1.w, d1.w);
    return r;
}

template<int K, int KS, int M, bool YH, bool AF1, bool AF2>
__global__ __launch_bounds__(256) void gemm_mfma(
    const ushort* __restrict__ A1, const ushort* __restrict__ A2,
    const float* __restrict__ su1, const float* __restrict__ sq1_,
    const float* __restrict__ g1, const float* __restrict__ be1,
    const float* __restrict__ su2, const float* __restrict__ sq2_,
    const float* __restrict__ g2, const float* __restrict__ be2,
    const ushort* __restrict__ Wp, const float* __restrict__ bias,
    void* __restrict__ Yv, float* __restrict__ sum, float* __restrict__ sq,
    int N, float invN)
{
    constexpr int NCT = M / 16;
    constexpr int NKC = K / 32;
    __shared__ float redS[4][M];
    __shared__ float redQ[4][M];
    __shared__ float scL[K];
    __shared__ float shL[K];
    const int tid = threadIdx.x;
    if constexpr (AF1 || AF2) {
        for (int i = tid; i < K; i += 256) {
            float s_, q_, g_, b_;
            if (i < KS) { s_ = su1[i]; q_ = sq1_[i]; g_ = g1[i]; b_ = be1[i]; }
            else        { s_ = su2[i - KS]; q_ = sq2_[i - KS]; g_ = g2[i - KS]; b_ = be2[i - KS]; }
            const float m = s_ * invN;
            const float c = g_ * rsqrtf(q_ * invN - m * m + BN_EPS);
            scL[i] = c; shL[i] = b_ - m * c;
        }
        __syncthreads();
    }
    const int w = tid >> 6, l = tid & 63;
    const int col = l & 15, kg = l >> 4;
    const int rowA = blockIdx.x * 64 + w * 16 + col;
    const int rA = (rowA < N) ? rowA : (N - 1);
    f32x4 acc[NCT];
#pragma unroll
    for (int ct = 0; ct < NCT; ++ct) acc[ct] = f32x4{0.f, 0.f, 0.f, 0.f};
#pragma unroll
    for (int kc = 0; kc < NKC; ++kc) {
        const int kbase = kc * 32 + kg * 8;
        half8 a;
        if constexpr (KS < K) {
            if (kbase >= KS) {
                a = *(const half8*)(A2 + (size_t)rA * (K - KS) + (kbase - KS));
                if constexpr (AF2) a = affine_h8(a, scL, shL, kbase);
            } else {
                a = *(const half8*)(A1 + (size_t)rA * KS + kbase);
                if constexpr (AF1) a = affine_h8(a, scL, shL, kbase);
            }
        } else {
            a = *(const half8*)(A1 + (size_t)rA * K + kbase);
            if constexpr (AF1) a = affine_h8(a, scL, shL, kbase);
        }
#pragma unroll
        for (int ct = 0; ct < NCT; ++ct) {
            const half8 wf = *(const half8*)(Wp + ((size_t)(kc * NCT + ct) * 64 + l) * 8);
            acc[ct] = __builtin_amdgcn_mfma_f32_16x16x32_f16(a, wf, acc[ct], 0, 0, 0);
        }
    }
    const int row0 = blockIdx.x * 64 + w * 16 + 4 * kg;
#pragma unroll
    for (int ct = 0; ct < NCT; ++ct) {
        const float bs = bias[ct * 16 + col];
        float sS = 0.f, sQ = 0.f;
#pragma unroll
        for (int r = 0; r < 4; ++r) {
            const int ro = row0 + r;
            if (ro < N) {
                const float o = fmaxf(acc[ct][r] + bs, 0.f);
                if constexpr (YH) ((ushort*)Yv)[(size_t)ro * M + ct * 16 + col] = f2h(o);
                else              ((float*)Yv)[(size_t)ro * M + ct * 16 + col] = o;
                sS += o; sQ = fmaf(o, o, sQ);
            }
        }
        sS += __shfl_xor(sS, 16, 64); sQ += __shfl_xor(sQ, 16, 64);
        sS += __shfl_xor(sS, 32, 64); sQ += __shfl_xor(sQ, 32, 64);
        if (l < 16) { redS[w][ct * 16 + col] = sS; redQ[w][ct * 16 + col] = sQ; }
    }
    __syncthreads();
    for (int i = tid; i < M; i += 256) {
        const float S = redS[0][i] + redS[1][i] + redS[2][i] + redS[3][i];
        const float Q = redQ[0][i] + redQ[1][i] + redQ[2][i] + redQ[3][i];
        unsafeAtomicAdd(&sum[i], S);
        unsafeAtomicAdd(&sq[i], Q);
    }
}

// final BN apply (scale/shift computed inline from raw stats) -> out [N,10]
__global__ __launch_bounds__(256) void bn_apply_final(
    const float* __restrict__ Y16, const float* __restrict__ su,
    const float* __restrict__ qu, const float* __restrict__ g5,
    const float* __restrict__ be5, float* __restrict__ out, int total, float invN)
{
    for (int i = blockIdx.x * 256 + threadIdx.x; i < total; i += gridDim.x * 256) {
        const int n = i / 10;
        const int c = i - n * 10;
        const float m = su[c] * invN;
        const float sc = g5[c] * rsqrtf(qu[c] * invN - m * m + BN_EPS);
        const float sh = be5[c] - m * sc;
        out[i] = fmaf(Y16[(size_t)n * 16 + c], sc, sh);
    }
}

// ---------------------------------------------------------------------------
extern "C" void kernel_launch(void* const* d_in, const int* in_sizes, int n_in,
                              void* d_out, int out_size, void* d_ws, size_t ws_size,
                              hipStream_t stream)
{
    const float* x   = (const float*)d_in[0];
    const float* ea  = (const float*)d_in[1];
    const int*   ei  = (const int*)d_in[2];
    const float* lw  = (const float*)d_in[3];
    const float* lb  = (const float*)d_in[4];
    const float* w1  = (const float*)d_in[5];
    const float* b1  = (const float*)d_in[6];
    const float* g1  = (const float*)d_in[7];
    const float* be1 = (const float*)d_in[8];
    const float* w2  = (const float*)d_in[9];
    const float* b2  = (const float*)d_in[10];
    const float* g2  = (const float*)d_in[11];
    const float* be2 = (const float*)d_in[12];
    const float* w3  = (const float*)d_in[13];
    const float* b3  = (const float*)d_in[14];
    const float* g3  = (const float*)d_in[15];
    const float* be3 = (const float*)d_in[16];
    const float* w4  = (const float*)d_in[17];
    const float* b4  = (const float*)d_in[18];
    const float* g4  = (const float*)d_in[19];
    const float* be4 = (const float*)d_in[20];
    const float* w5  = (const float*)d_in[21];
    const float* b5  = (const float*)d_in[22];
    const float* g5  = (const float*)d_in[23];
    const float* be5 = (const float*)d_in[24];

    const int N = in_sizes[0] / 128;   // 50000
    const int E = in_sizes[1];         // 1600000
    const int* src = ei;
    const int* dst = ei + E;
    const float invN = 1.0f / (float)N;

    float* ws = (float*)d_ws;
    // fp16 pools (offsets in float units)
    ushort* Pa = (ushort*)ws;                           // N*128 h: xh -> y1h
    ushort* Pb = (ushort*)(ws + (size_t)N * 64);        // N*128 h: t1h -> t2h -> y3h
    ushort* Pc = (ushort*)(ws + (size_t)N * 128);       // N*64 h:  y2h
    ushort* Pd = (ushort*)(ws + (size_t)N * 160);       // N*96 h:  y4h
    float*  y5 = ws + (size_t)N * 208;                  // N*16 f32
    float*  smallr = ws + (size_t)N * 224;
    float*  sums   = smallr;                            // 10 x 128
    float*  b5p    = smallr + 1280;                     // 16
    uint*   lwh    = (uint*)(smallr + 1296);            // 64
    uint*   lbh    = lwh + 64;                          // 64
    ushort* Wp     = (ushort*)(smallr + 1424);          // 53760 halves
    int*    ibase  = (int*)(smallr + 1424 + 26880);
    int*    H      = ibase;                             // NB*NBLK (+pad) = 100160
    int*    bsum   = H + 100160;                        // 128
    uint*   tmp_e  = (uint*)(bsum + 128);               // E uint
    uchar*  tmp_d  = (uchar*)(tmp_e + E);               // E bytes
    uint*   edges  = (uint*)(tmp_d + ((E + 3) & ~3));   // E uint
    int*    off    = (int*)(edges + E);                 // N+1
#define SUM(l)   (sums + (l) * 128)
#define SQ(l)    (sums + (5 + (l)) * 128)

    pack_all<<<216, 256, 0, stream>>>(w1, w2, w3, w4, w5, b5, lw, lb, Wp, b5p, sums, lwh, lbh);
    cvt_f16<<<2048, 256, 0, stream>>>(x, Pa, N * 32);   // xh -> Pa

    // ---- CSR build (reused by both convs)
    const int NB   = (N + 127) / 128;                   // 391 coarse buckets
    const int NBLK = 256;
    const int nH   = NB * NBLK;                         // 100096
    const int nbH  = (nH + 1023) / 1024;                // 98
    hist_blocks<<<NBLK, 256, 0, stream>>>(dst, H, E, NB, NBLK);
    scan1<<<nbH, 1024, 0, stream>>>(H, H, bsum, nH);
    scan2<<<1, 64, 0, stream>>>(bsum, nbH);
    scan3<<<nbH, 1024, 0, stream>>>(H, bsum, nH);
    scatter_coarse<<<NBLK, 256, 0, stream>>>(src, dst, ea, H, tmp_e, tmp_d, E, NB, NBLK);
    fill_fine2<<<NB, 256, 0, stream>>>(tmp_e, tmp_d, H, off, edges, N, E, NBLK);

    const int gemmGrid = (N + 63) / 64;                 // 782
    const int aggrGrid = (N + 15) / 16;                 // 3125

    // ---- conv1: t1 = x + sum relu(x[src]+e);  y1 = relu(t1@w1+b1) + stats
    gine_aggr<false><<<aggrGrid, 256, 0, stream>>>(
        Pa, off, edges, lwh, lbh, nullptr, nullptr, nullptr, nullptr, invN, Pb, N);
    gemm_mfma<128, 128, 128, true, false, false><<<gemmGrid, 256, 0, stream>>>(
        Pb, nullptr, nullptr, nullptr, nullptr, nullptr,
        nullptr, nullptr, nullptr, nullptr,
        Wp, b1, Pa, SUM(0), SQ(0), N, invN);                               // y1h -> Pa

    // ---- conv2: t2 = bn(y1) + sum relu(bn(y1)[src]+e)  (affine from stats)
    gine_aggr<true><<<aggrGrid, 256, 0, stream>>>(
        Pa, off, edges, lwh, lbh, SUM(0), SQ(0), g1, be1, invN, Pb, N);    // t2h -> Pb
    gemm_mfma<128, 128, 64, true, false, false><<<gemmGrid, 256, 0, stream>>>(
        Pb, nullptr, nullptr, nullptr, nullptr, nullptr,
        nullptr, nullptr, nullptr, nullptr,
        Wp + 16384, b2, Pc, SUM(1), SQ(1), N, invN);                       // y2h -> Pc

    // ---- lin1: y3 = relu(concat(bn(y1), bn(y2)) @ w3 + b3) (K split 128|64)
    gemm_mfma<192, 128, 96, true, true, true><<<gemmGrid, 256, 0, stream>>>(
        Pa, Pc, SUM(0), SQ(0), g1, be1, SUM(1), SQ(1), g2, be2,
        Wp + 24576, b3, Pb, SUM(2), SQ(2), N, invN);                       // y3h -> Pb

    // ---- mlp1 layer 1: y4 = relu(bn(y3) @ w4 + b4)
    gemm_mfma<96, 96, 96, true, true, false><<<gemmGrid, 256, 0, stream>>>(
        Pb, nullptr, SUM(2), SQ(2), g3, be3, nullptr, nullptr, nullptr, nullptr,
        Wp + 43008, b4, Pd, SUM(3), SQ(3), N, invN);                       // y4h -> Pd

    // ---- mlp1 layer 2: y5 = relu(bn(y4) @ w5p + b5p) [N,16] f32
    gemm_mfma<96, 96, 16, false, true, false><<<gemmGrid, 256, 0, stream>>>(
        Pd, nullptr, SUM(3), SQ(3), g4, be4, nullptr, nullptr, nullptr, nullptr,
        Wp + 52224, b5p, y5, SUM(4), SQ(4), N, invN);

    // ---- final BN apply -> out [N,10]
    bn_apply_final<<<1024, 256, 0, stream>>>(y5, SUM(4), SQ(4), g5, be5,
                                             (float*)d_out, N * 10, invN);
#undef SUM
#undef SQ
}

// Round 13
// 300.072 us; speedup vs baseline: 1.3825x; 1.0883x over previous
//
#include <hip/hip_runtime.h>
#include <hip/hip_fp16.h>

static constexpr float BN_EPS = 1e-5f;

using half8 = __attribute__((ext_vector_type(8))) _Float16;
using f32x4 = __attribute__((ext_vector_type(4))) float;

__device__ __forceinline__ ushort f2h(float f) {
    return __half_as_ushort(__float2half(f));           // RNE
}
__device__ __forceinline__ __half2 u2h2(uint u) {
    union { uint u; __half2 h; } c; c.u = u; return c.h;
}
__device__ __forceinline__ uint h22u(__half2 h) {
    union { uint u; __half2 h; } c; c.h = h; return c.u;
}
__device__ __forceinline__ float h2f1(ushort u) {
    __half h = *reinterpret_cast<__half*>(&u);
    return __half2float(h);
}
__device__ __forceinline__ uint pk2(float a, float b) {
    return (uint)f2h(a) | ((uint)f2h(b) << 16);
}
// packed relu on a half2 word: zero any half with sign bit set
__device__ __forceinline__ uint relu2u(uint u) {
    return u & ~(((u >> 15) & 0x10001u) * 0xFFFFu);
}

// ---------------------------------------------------------------------------
// Fused setup: fp32->fp16 convert of x (grid-stride) + weight pack + b5 pad +
// stats zero + lw/lb half2 pack. One launch.
// ---------------------------------------------------------------------------
__device__ __forceinline__ void pack_store(ushort* dst, int M, int k, int c, float v)
{
    const int kc = k >> 5, kk = k & 31, ct = c >> 4;
    const int lane = (c & 15) | ((kk >> 3) << 4);
    const int j = kk & 7;
    dst[((size_t)(kc * (M / 16) + ct) * 64 + lane) * 8 + j] = f2h(v);
}

__global__ __launch_bounds__(256) void setup_fused(
    const float* __restrict__ x, ushort* __restrict__ xh, int n4,
    const float* __restrict__ w1, const float* __restrict__ w2,
    const float* __restrict__ w3, const float* __restrict__ w4,
    const float* __restrict__ w5, const float* __restrict__ b5,
    const float* __restrict__ lw, const float* __restrict__ lb,
    ushort* __restrict__ Wp, float* __restrict__ b5p, float* __restrict__ sums,
    uint* __restrict__ lwh, uint* __restrict__ lbh)
{
    const int gid = blockIdx.x * 256 + threadIdx.x;
    const int stride = gridDim.x * 256;
    for (int i = gid; i < n4; i += stride) {
        const float4 v = ((const float4*)x)[i];
        ushort4 u;
        u.x = f2h(v.x); u.y = f2h(v.y); u.z = f2h(v.z); u.w = f2h(v.w);
        ((ushort4*)xh)[i] = u;
    }
    int t = gid;
    if (t < 16384) { pack_store(Wp, 128, t / 128, t % 128, w1[t]); return; }
    t -= 16384;
    if (t < 8192) { pack_store(Wp + 16384, 64, t / 64, t % 64, w2[t]); return; }
    t -= 8192;
    if (t < 18432) { pack_store(Wp + 24576, 96, t / 96, t % 96, w3[t]); return; }
    t -= 18432;
    if (t < 9216) { pack_store(Wp + 43008, 96, t / 96, t % 96, w4[t]); return; }
    t -= 9216;
    if (t < 1536) {
        const int k = t / 16, c = t % 16;
        pack_store(Wp + 52224, 16, k, c, (c < 10) ? w5[k * 10 + c] : 0.f);
        return;
    }
    t -= 1536;
    if (t < 16) { b5p[t] = (t < 10) ? b5[t] : 0.f; return; }
    t -= 16;
    if (t < 1280) { sums[t] = 0.f; return; }
    t -= 1280;
    if (t < 64) { lwh[t] = pk2(lw[2 * t], lw[2 * t + 1]); return; }
    t -= 64;
    if (t < 64) { lbh[t] = pk2(lb[2 * t], lb[2 * t + 1]); return; }
}

// ---------------------------------------------------------------------------
// CSR build: radix-style two-pass counting sort by dst, no global atomics.
// ---------------------------------------------------------------------------
__device__ inline int wave_incl_scan(int v, int lane)
{
#pragma unroll
    for (int s = 1; s < 64; s <<= 1) {
        const int t = __shfl_up(v, s, 64);
        if (lane >= s) v += t;
    }
    return v;
}

__global__ __launch_bounds__(1024) void scan1(
    const int* __restrict__ cnt, int* __restrict__ off, int* __restrict__ bsum, int n)
{
    __shared__ int wsum[16];
    const int tid = threadIdx.x, lane = tid & 63, wid = tid >> 6;
    const int i = blockIdx.x * 1024 + tid;
    const int v = (i < n) ? cnt[i] : 0;
    const int incl = wave_incl_scan(v, lane);
    if (lane == 63) wsum[wid] = incl;
    __syncthreads();
    if (wid == 0) {
        int wv = (lane < 16) ? wsum[lane] : 0;
        wv = wave_incl_scan(wv, lane);
        if (lane < 16) wsum[lane] = wv;
    }
    __syncthreads();
    const int excl = (wid > 0 ? wsum[wid - 1] : 0) + incl - v;
    if (i < n) off[i] = excl;
    if (tid == 1023) bsum[blockIdx.x] = wsum[15];
}

// scan3 with scan2 fused: each block serially prefixes the (<=128) block
// totals up to its own blockIdx (thread 0), then adds.
__global__ __launch_bounds__(1024) void scan3f(
    int* __restrict__ off, const int* __restrict__ bsum, int n)
{
    __shared__ int pre;
    if (threadIdx.x == 0) {
        int s = 0;
        for (int j = 0; j < (int)blockIdx.x; ++j) s += bsum[j];
        pre = s;
    }
    __syncthreads();
    const int i = blockIdx.x * 1024 + threadIdx.x;
    if (i < n) off[i] += pre;
}

// per-(bucket,block) histogram, bucket-major layout H[b*NBLK + blk]
__global__ __launch_bounds__(256) void hist_blocks(
    const int* __restrict__ dst, int* __restrict__ H, int E, int NB, int NBLK)
{
    __shared__ int h[512];
    for (int i = threadIdx.x; i < NB; i += 256) h[i] = 0;
    __syncthreads();
    const int chunk = (E + NBLK - 1) / NBLK;
    const int beg = blockIdx.x * chunk;
    const int end = min(beg + chunk, E);
    for (int i = beg + threadIdx.x; i < end; i += 256)
        atomicAdd(&h[dst[i] >> 7], 1);
    __syncthreads();
    for (int i = threadIdx.x; i < NB; i += 256)
        H[(size_t)i * NBLK + blockIdx.x] = h[i];
}

// deterministic coarse scatter; tmp_e = src|f16(ea)<<16 (final edge payload),
// tmp_d = dst&127 (fine bucket key)
__global__ __launch_bounds__(256) void scatter_coarse(
    const int* __restrict__ src, const int* __restrict__ dst,
    const float* __restrict__ ea, const int* __restrict__ H,
    uint* __restrict__ tmp_e, uchar* __restrict__ tmp_d, int E, int NB, int NBLK)
{
    __shared__ int h[512];
    for (int i = threadIdx.x; i < NB; i += 256)
        h[i] = H[(size_t)i * NBLK + blockIdx.x];
    __syncthreads();
    const int chunk = (E + NBLK - 1) / NBLK;
    const int beg = blockIdx.x * chunk;
    const int end = min(beg + chunk, E);
    for (int i = beg + threadIdx.x; i < end; i += 256) {
        const int d = dst[i];
        const int pos = atomicAdd(&h[d >> 7], 1);
        tmp_e[pos] = (uint)(src[i] & 0xFFFF) | ((uint)f2h(ea[i]) << 16);
        tmp_d[pos] = (uchar)(d & 127);
    }
}

// per-bucket fine scatter; derives per-node off; edges[pos] = tmp_e[i]
__global__ __launch_bounds__(256) void fill_fine2(
    const uint* __restrict__ tmp_e, const uchar* __restrict__ tmp_d,
    const int* __restrict__ H, int* __restrict__ off, uint* __restrict__ edges,
    int N, int E, int NBLK)
{
    __shared__ int cnt[128];
    __shared__ int wtot;
    const int b = blockIdx.x;
    const int base = b * 128;
    const int tid = threadIdx.x;
    const int lo = H[(size_t)b * NBLK];
    const int hi = (b + 1 < (int)gridDim.x) ? H[(size_t)(b + 1) * NBLK] : E;
    if (tid < 128) cnt[tid] = 0;
    __syncthreads();
    for (int i = lo + tid; i < hi; i += 256)
        atomicAdd(&cnt[tmp_d[i]], 1);
    __syncthreads();
    int excl = 0;
    if (tid < 128) {
        const int v = cnt[tid];
        const int incl = wave_incl_scan(v, tid & 63);
        if (tid == 63) wtot = incl;
        excl = incl - v;
    }
    __syncthreads();
    if (tid >= 64 && tid < 128) excl += wtot;
    if (tid < 128) {
        const int o = lo + excl;
        if (base + tid < N) off[base + tid] = o;
        cnt[tid] = o;                         // reuse as heads
    }
    if (b == 0 && tid == 0) off[N] = E;
    __syncthreads();
    for (int i = lo + tid; i < hi; i += 256) {
        const int dl = tmp_d[i];
        const uint pe = tmp_e[i];
        const int pos = atomicAdd(&cnt[dl], 1);
        edges[pos] = pe;
    }
}

// ---------------------------------------------------------------------------
// GINE aggregation (CSR): 16 lanes/node (8 cols/lane, uint4 gather), 4 nodes
// per wave, BRANCH-FREE depth-2 pipeline (unconditional prefetch of edge p+2;
// overruns into next node's list / 2 zero sentinels — valid memory, never
// consumed). Packed fp16 math, fp16 accumulators. AFF: BN from raw stats.
// outh[node] = fp16( bn(xh[node]) + sum_p relu(bn(xh[src_p]) + a_p*lw + lb) )
// ---------------------------------------------------------------------------
template<bool AFF>
__global__ __launch_bounds__(256) void gine_aggr(
    const ushort* __restrict__ xh, const int* __restrict__ off,
    const uint* __restrict__ edges, const uint* __restrict__ lwh,
    const uint* __restrict__ lbh, const float* __restrict__ su,
    const float* __restrict__ qu, const float* __restrict__ g,
    const float* __restrict__ be, float invN,
    ushort* __restrict__ outh, int N)
{
    const int q = threadIdx.x & 15;                 // cols 8q .. 8q+7
    const int node = blockIdx.x * 16 + (threadIdx.x >> 4);
    if (node >= N) return;
    __half2 lw[4], lb[4], sc[4], sh[4];
#pragma unroll
    for (int i = 0; i < 4; ++i) {
        lw[i] = u2h2(lwh[q * 4 + i]);
        lb[i] = u2h2(lbh[q * 4 + i]);
    }
    if constexpr (AFF) {
        const int c0 = q * 8;
#pragma unroll
        for (int i = 0; i < 4; ++i) {
            const float2 s2 = *(const float2*)(su + c0 + 2 * i);
            const float2 q2 = *(const float2*)(qu + c0 + 2 * i);
            const float2 g2 = *(const float2*)(g + c0 + 2 * i);
            const float2 b2 = *(const float2*)(be + c0 + 2 * i);
            const float m0 = s2.x * invN, m1 = s2.y * invN;
            const float c0f = g2.x * rsqrtf(q2.x * invN - m0 * m0 + BN_EPS);
            const float c1f = g2.y * rsqrtf(q2.y * invN - m1 * m1 + BN_EPS);
            sc[i] = u2h2(pk2(c0f, c1f));
            sh[i] = u2h2(pk2(b2.x - m0 * c0f, b2.y - m1 * c1f));
        }
    }
    __half2 acc[4];
    {
        const uint4 u = ((const uint4*)(xh + (size_t)node * 128))[q];
        acc[0] = u2h2(u.x); acc[1] = u2h2(u.y); acc[2] = u2h2(u.z); acc[3] = u2h2(u.w);
        if constexpr (AFF) {
#pragma unroll
            for (int i = 0; i < 4; ++i) acc[i] = __hfma2(acc[i], sc[i], sh[i]);
        }
    }

    auto proc = [&](uint e, uint4 u) {
        const __half2 a2 = u2h2((e >> 16) * 0x10001u);
        uint ua[4] = {u.x, u.y, u.z, u.w};
#pragma unroll
        for (int i = 0; i < 4; ++i) {
            __half2 x2 = u2h2(ua[i]);
            if constexpr (AFF) x2 = __hfma2(x2, sc[i], sh[i]);
            __half2 m = __hfma2(a2, lw[i], lb[i]);
            m = __hadd2(x2, m);
            m = u2h2(relu2u(h22u(m)));           // packed relu (bit trick)
            acc[i] = __hadd2(acc[i], m);
        }
    };

    const int p0 = off[node];
    const int pend = off[node + 1];
    if (p0 < pend) {
        uint e0 = edges[p0];
        uint4 u0 = ((const uint4*)(xh + (size_t)(e0 & 0xFFFFu) * 128))[q];
        uint e1 = edges[p0 + 1];                 // may overrun node's list: valid mem
        uint4 u1 = ((const uint4*)(xh + (size_t)(e1 & 0xFFFFu) * 128))[q];
        for (int p = p0; p < pend; ++p) {
            const uint e2 = edges[p + 2];        // unconditional prefetch
            const uint4 u2 = ((const uint4*)(xh + (size_t)(e2 & 0xFFFFu) * 128))[q];
            proc(e0, u0);
            e0 = e1; u0 = u1;
            e1 = e2; u1 = u2;
        }
    }
    uint4 o;
    o.x = h22u(acc[0]); o.y = h22u(acc[1]); o.z = h22u(acc[2]); o.w = h22u(acc[3]);
    ((uint4*)(outh + (size_t)node * 128))[q] = o;
}

// ---------------------------------------------------------------------------
// MFMA fp16 GEMM + bias + relu + BN-stats epilogue + optional per-k input
// affine. 128 rows/block (each wave: two 16-row groups, W fragment reused).
// Affine scale/shift computed in an LDS prologue from raw stats.
// ---------------------------------------------------------------------------
__device__ __forceinline__ half8 affine_h8(
    half8 a, const float* sc, const float* sh, int k)
{
    const float4 c0 = *(const float4*)(sc + k), c1 = *(const float4*)(sc + k + 4);
    const float4 d0 = *(const float4*)(sh + k), d1 = *(const float4*)(sh + k + 4);
    half8 r;
    r[0] = (_Float16)fmaf((float)a[0], c0.x, d0.x);
    r[1] = (_Float16)fmaf((float)a[1], c0.y, d0.y);
    r[2] = (_Float16)fmaf((float)a[2], c0.z, d0.z);
    r[3] = (_Float16)fmaf((float)a[3], c0.w, d0.w);
    r[4] = (_Float16)fmaf((float)a[4], c1.x, d1.x);
    r[5] = (_Float16)fmaf((float)a[5], c1.y, d1.y);
    r[6] = (_Float16)fmaf((float)a[6], c1.z, d1.z);
    r[7] = (_Float16)fmaf((float)a[7], c1.w, d1.w);
    return r;
}

template<int K, int KS, int M, bool YH, bool AF1, bool AF2>
__global__ __launch_bounds__(256) void gemm_mfma(
    const ushort* __restrict__ A1, const ushort* __restrict__ A2,
    const float* __restrict__ su1, const float* __restrict__ sq1_,
    const float* __restrict__ g1, const float* __restrict__ be1,
    const float* __restrict__ su2, const float* __restrict__ sq2_,
    const float* __restrict__ g2, const float* __restrict__ be2,
    const ushort* __restrict__ Wp, const float* __restrict__ bias,
    void* __restrict__ Yv, float* __restrict__ sum, float* __restrict__ sq,
    int N, float invN)
{
    constexpr int NCT = M / 16;
    constexpr int NKC = K / 32;
    __shared__ float redS[4][M];
    __shared__ float redQ[4][M];
    __shared__ float scL[K];
    __shared__ float shL[K];
    const int tid = threadIdx.x;
    if constexpr (AF1 || AF2) {
        for (int i = tid; i < K; i += 256) {
            float s_, q_, g_, b_;
            if (i < KS) { s_ = su1[i]; q_ = sq1_[i]; g_ = g1[i]; b_ = be1[i]; }
            else        { s_ = su2[i - KS]; q_ = sq2_[i - KS]; g_ = g2[i - KS]; b_ = be2[i - KS]; }
            const float m = s_ * invN;
            const float c = g_ * rsqrtf(q_ * invN - m * m + BN_EPS);
            scL[i] = c; shL[i] = b_ - m * c;
        }
        __syncthreads();
    }
    const int w = tid >> 6, l = tid & 63;
    const int col = l & 15, kg = l >> 4;
    const int rowAa = blockIdx.x * 128 + w * 16 + col;
    const int rowAb = rowAa + 64;
    const int rAa = (rowAa < N) ? rowAa : (N - 1);
    const int rAb = (rowAb < N) ? rowAb : (N - 1);
    f32x4 accA[NCT], accB[NCT];
#pragma unroll
    for (int ct = 0; ct < NCT; ++ct) {
        accA[ct] = f32x4{0.f, 0.f, 0.f, 0.f};
        accB[ct] = f32x4{0.f, 0.f, 0.f, 0.f};
    }
    auto loadA = [&](int rA, int kbase) -> half8 {
        half8 a;
        if constexpr (KS < K) {
            if (kbase >= KS) {
                a = *(const half8*)(A2 + (size_t)rA * (K - KS) + (kbase - KS));
                if constexpr (AF2) a = affine_h8(a, scL, shL, kbase);
            } else {
                a = *(const half8*)(A1 + (size_t)rA * KS + kbase);
                if constexpr (AF1) a = affine_h8(a, scL, shL, kbase);
            }
        } else {
            a = *(const half8*)(A1 + (size_t)rA * K + kbase);
            if constexpr (AF1) a = affine_h8(a, scL, shL, kbase);
        }
        return a;
    };
#pragma unroll
    for (int kc = 0; kc < NKC; ++kc) {
        const int kbase = kc * 32 + kg * 8;
        const half8 aA = loadA(rAa, kbase);
        const half8 aB = loadA(rAb, kbase);
#pragma unroll
        for (int ct = 0; ct < NCT; ++ct) {
            const half8 wf = *(const half8*)(Wp + ((size_t)(kc * NCT + ct) * 64 + l) * 8);
            accA[ct] = __builtin_amdgcn_mfma_f32_16x16x32_f16(aA, wf, accA[ct], 0, 0, 0);
            accB[ct] = __builtin_amdgcn_mfma_f32_16x16x32_f16(aB, wf, accB[ct], 0, 0, 0);
        }
    }
    const int row0a = blockIdx.x * 128 + w * 16 + 4 * kg;
    const int row0b = row0a + 64;
#pragma unroll
    for (int ct = 0; ct < NCT; ++ct) {
        const float bs = bias[ct * 16 + col];
        float sS = 0.f, sQ = 0.f;
#pragma unroll
        for (int r = 0; r < 4; ++r) {
            const int ro = row0a + r;
            if (ro < N) {
                const float o = fmaxf(accA[ct][r] + bs, 0.f);
                if constexpr (YH) ((ushort*)Yv)[(size_t)ro * M + ct * 16 + col] = f2h(o);
                else              ((float*)Yv)[(size_t)ro * M + ct * 16 + col] = o;
                sS += o; sQ = fmaf(o, o, sQ);
            }
        }
#pragma unroll
        for (int r = 0; r < 4; ++r) {
            const int ro = row0b + r;
            if (ro < N) {
                const float o = fmaxf(accB[ct][r] + bs, 0.f);
                if constexpr (YH) ((ushort*)Yv)[(size_t)ro * M + ct * 16 + col] = f2h(o);
                else              ((float*)Yv)[(size_t)ro * M + ct * 16 + col] = o;
                sS += o; sQ = fmaf(o, o, sQ);
            }
        }
        sS += __shfl_xor(sS, 16, 64); sQ += __shfl_xor(sQ, 16, 64);
        sS += __shfl_xor(sS, 32, 64); sQ += __shfl_xor(sQ, 32, 64);
        if (l < 16) { redS[w][ct * 16 + col] = sS; redQ[w][ct * 16 + col] = sQ; }
    }
    __syncthreads();
    for (int i = tid; i < M; i += 256) {
        const float S = redS[0][i] + redS[1][i] + redS[2][i] + redS[3][i];
        const float Q = redQ[0][i] + redQ[1][i] + redQ[2][i] + redQ[3][i];
        unsafeAtomicAdd(&sum[i], S);
        unsafeAtomicAdd(&sq[i], Q);
    }
}

// final BN apply (scale/shift computed inline from raw stats) -> out [N,10]
__global__ __launch_bounds__(256) void bn_apply_final(
    const ushort* __restrict__ Y16h, const float* __restrict__ su,
    const float* __restrict__ qu, const float* __restrict__ g5,
    const float* __restrict__ be5, float* __restrict__ out, int total, float invN)
{
    for (int i = blockIdx.x * 256 + threadIdx.x; i < total; i += gridDim.x * 256) {
        const int n = i / 10;
        const int c = i - n * 10;
        const float m = su[c] * invN;
        const float sc = g5[c] * rsqrtf(qu[c] * invN - m * m + BN_EPS);
        const float sh = be5[c] - m * sc;
        out[i] = fmaf(h2f1(Y16h[(size_t)n * 16 + c]), sc, sh);
    }
}

// ---------------------------------------------------------------------------
extern "C" void kernel_launch(void* const* d_in, const int* in_sizes, int n_in,
                              void* d_out, int out_size, void* d_ws, size_t ws_size,
                              hipStream_t stream)
{
    const float* x   = (const float*)d_in[0];
    const float* ea  = (const float*)d_in[1];
    const int*   ei  = (const int*)d_in[2];
    const float* lw  = (const float*)d_in[3];
    const float* lb  = (const float*)d_in[4];
    const float* w1  = (const float*)d_in[5];
    const float* b1  = (const float*)d_in[6];
    const float* g1  = (const float*)d_in[7];
    const float* be1 = (const float*)d_in[8];
    const float* w2  = (const float*)d_in[9];
    const float* b2  = (const float*)d_in[10];
    const float* g2  = (const float*)d_in[11];
    const float* be2 = (const float*)d_in[12];
    const float* w3  = (const float*)d_in[13];
    const float* b3  = (const float*)d_in[14];
    const float* g3  = (const float*)d_in[15];
    const float* be3 = (const float*)d_in[16];
    const float* w4  = (const float*)d_in[17];
    const float* b4  = (const float*)d_in[18];
    const float* g4  = (const float*)d_in[19];
    const float* be4 = (const float*)d_in[20];
    const float* w5  = (const float*)d_in[21];
    const float* b5  = (const float*)d_in[22];
    const float* g5  = (const float*)d_in[23];
    const float* be5 = (const float*)d_in[24];

    const int N = in_sizes[0] / 128;   // 50000
    const int E = in_sizes[1];         // 1600000
    const int* src = ei;
    const int* dst = ei + E;
    const float invN = 1.0f / (float)N;

    float* ws = (float*)d_ws;
    // fp16 pools (offsets in float units)
    ushort* Pa = (ushort*)ws;                           // N*128 h: xh -> y1h
    ushort* Pb = (ushort*)(ws + (size_t)N * 64);        // N*128 h: t1h -> t2h -> y3h
    ushort* Pc = (ushort*)(ws + (size_t)N * 128);       // N*64 h:  y2h
    ushort* Pd = (ushort*)(ws + (size_t)N * 160);       // N*96 h:  y4h
    ushort* y5h = (ushort*)(ws + (size_t)N * 208);      // N*16 h
    float*  smallr = ws + (size_t)N * 224;
    float*  sums   = smallr;                            // 10 x 128
    float*  b5p    = smallr + 1280;                     // 16
    uint*   lwh    = (uint*)(smallr + 1296);            // 64
    uint*   lbh    = lwh + 64;                          // 64
    ushort* Wp     = (ushort*)(smallr + 1424);          // 53760 halves
    int*    ibase  = (int*)(smallr + 1424 + 26880);
    int*    H      = ibase;                             // NB*NBLK (+pad) = 100160
    int*    bsum   = H + 100160;                        // 128
    uint*   tmp_e  = (uint*)(bsum + 128);               // E uint
    uchar*  tmp_d  = (uchar*)(tmp_e + E);               // E bytes
    uint*   edges  = (uint*)(tmp_d + ((E + 3) & ~3));   // E+2 uint (2 sentinels)
    int*    off    = (int*)(edges + E + 2);             // N+1
#define SUM(l)   (sums + (l) * 128)
#define SQ(l)    (sums + (5 + (l)) * 128)

    setup_fused<<<2048, 256, 0, stream>>>(x, Pa, N * 32, w1, w2, w3, w4, w5, b5,
                                          lw, lb, Wp, b5p, sums, lwh, lbh);
    hipMemsetAsync(edges + E, 0, 2 * sizeof(uint), stream);   // prefetch sentinels

    // ---- CSR build (reused by both convs)
    const int NB   = (N + 127) / 128;                   // 391 coarse buckets
    const int NBLK = 256;
    const int nH   = NB * NBLK;                         // 100096
    const int nbH  = (nH + 1023) / 1024;                // 98
    hist_blocks<<<NBLK, 256, 0, stream>>>(dst, H, E, NB, NBLK);
    scan1<<<nbH, 1024, 0, stream>>>(H, H, bsum, nH);
    scan3f<<<nbH, 1024, 0, stream>>>(H, bsum, nH);
    scatter_coarse<<<NBLK, 256, 0, stream>>>(src, dst, ea, H, tmp_e, tmp_d, E, NB, NBLK);
    fill_fine2<<<NB, 256, 0, stream>>>(tmp_e, tmp_d, H, off, edges, N, E, NBLK);

    const int gemmGrid = (N + 127) / 128;               // 391
    const int aggrGrid = (N + 15) / 16;                 // 3125

    // ---- conv1: t1 = x + sum relu(x[src]+e);  y1 = relu(t1@w1+b1) + stats
    gine_aggr<false><<<aggrGrid, 256, 0, stream>>>(
        Pa, off, edges, lwh, lbh, nullptr, nullptr, nullptr, nullptr, invN, Pb, N);
    gemm_mfma<128, 128, 128, true, false, false><<<gemmGrid, 256, 0, stream>>>(
        Pb, nullptr, nullptr, nullptr, nullptr, nullptr,
        nullptr, nullptr, nullptr, nullptr,
        Wp, b1, Pa, SUM(0), SQ(0), N, invN);                               // y1h -> Pa

    // ---- conv2: t2 = bn(y1) + sum relu(bn(y1)[src]+e)  (affine from stats)
    gine_aggr<true><<<aggrGrid, 256, 0, stream>>>(
        Pa, off, edges, lwh, lbh, SUM(0), SQ(0), g1, be1, invN, Pb, N);    // t2h -> Pb
    gemm_mfma<128, 128, 64, true, false, false><<<gemmGrid, 256, 0, stream>>>(
        Pb, nullptr, nullptr, nullptr, nullptr, nullptr,
        nullptr, nullptr, nullptr, nullptr,
        Wp + 16384, b2, Pc, SUM(1), SQ(1), N, invN);                       // y2h -> Pc

    // ---- lin1: y3 = relu(concat(bn(y1), bn(y2)) @ w3 + b3) (K split 128|64)
    gemm_mfma<192, 128, 96, true, true, true><<<gemmGrid, 256, 0, stream>>>(
        Pa, Pc, SUM(0), SQ(0), g1, be1, SUM(1), SQ(1), g2, be2,
        Wp + 24576, b3, Pb, SUM(2), SQ(2), N, invN);                       // y3h -> Pb

    // ---- mlp1 layer 1: y4 = relu(bn(y3) @ w4 + b4)
    gemm_mfma<96, 96, 96, true, true, false><<<gemmGrid, 256, 0, stream>>>(
        Pb, nullptr, SUM(2), SQ(2), g3, be3, nullptr, nullptr, nullptr, nullptr,
        Wp + 43008, b4, Pd, SUM(3), SQ(3), N, invN);                       // y4h -> Pd

    // ---- mlp1 layer 2: y5 = relu(bn(y4) @ w5p + b5p) [N,16] f16
    gemm_mfma<96, 96, 16, true, true, false><<<gemmGrid, 256, 0, stream>>>(
        Pd, nullptr, SUM(3), SQ(3), g4, be4, nullptr, nullptr, nullptr, nullptr,
        Wp + 52224, b5p, y5h, SUM(4), SQ(4), N, invN);

    // ---- final BN apply -> out [N,10]
    bn_apply_final<<<1024, 256, 0, stream>>>(y5h, SUM(4), SQ(4), g5, be5,
                                             (float*)d_out, N * 10, invN);
#undef SUM
#undef SQ
}

// Round 14
// 291.396 us; speedup vs baseline: 1.4236x; 1.0298x over previous
//
#include <hip/hip_runtime.h>
#include <hip/hip_fp16.h>

static constexpr float BN_EPS = 1e-5f;

using half8 = __attribute__((ext_vector_type(8))) _Float16;
using f32x4 = __attribute__((ext_vector_type(4))) float;

__device__ __forceinline__ ushort f2h(float f) {
    return __half_as_ushort(__float2half(f));           // RNE
}
__device__ __forceinline__ __half2 u2h2(uint u) {
    union { uint u; __half2 h; } c; c.u = u; return c.h;
}
__device__ __forceinline__ uint h22u(__half2 h) {
    union { uint u; __half2 h; } c; c.h = h; return c.u;
}
__device__ __forceinline__ float h2f1(ushort u) {
    __half h = *reinterpret_cast<__half*>(&u);
    return __half2float(h);
}
__device__ __forceinline__ uint pk2(float a, float b) {
    return (uint)f2h(a) | ((uint)f2h(b) << 16);
}
// packed relu on a half2 word: zero any half with sign bit set
__device__ __forceinline__ uint relu2u(uint u) {
    return u & ~(((u >> 15) & 0x10001u) * 0xFFFFu);
}

// ---------------------------------------------------------------------------
// Fused setup + histogram: fp32->fp16 convert of x, weight pack, b5 pad,
// stats zero, lw/lb half2 pack, AND per-(bucket,block) dst histogram.
// Grid = NBLK (256) blocks. One launch.
// ---------------------------------------------------------------------------
__device__ __forceinline__ void pack_store(ushort* dst, int M, int k, int c, float v)
{
    const int kc = k >> 5, kk = k & 31, ct = c >> 4;
    const int lane = (c & 15) | ((kk >> 3) << 4);
    const int j = kk & 7;
    dst[((size_t)(kc * (M / 16) + ct) * 64 + lane) * 8 + j] = f2h(v);
}

__global__ __launch_bounds__(256) void setup_hist(
    const float* __restrict__ x, ushort* __restrict__ xh, int n4,
    const float* __restrict__ w1, const float* __restrict__ w2,
    const float* __restrict__ w3, const float* __restrict__ w4,
    const float* __restrict__ w5, const float* __restrict__ b5,
    const float* __restrict__ lw, const float* __restrict__ lb,
    ushort* __restrict__ Wp, float* __restrict__ b5p, float* __restrict__ sums,
    uint* __restrict__ lwh, uint* __restrict__ lbh,
    const int* __restrict__ dst, int* __restrict__ H, int E, int NB, int NBLK)
{
    __shared__ int h[512];
    for (int i = threadIdx.x; i < NB; i += 256) h[i] = 0;
    __syncthreads();
    // histogram of this block's edge chunk
    {
        const int chunk = (E + NBLK - 1) / NBLK;
        const int beg = blockIdx.x * chunk;
        const int end = min(beg + chunk, E);
        for (int i = beg + threadIdx.x; i < end; i += 256)
            atomicAdd(&h[dst[i] >> 7], 1);
    }
    // x convert (grid-stride)
    const int gid = blockIdx.x * 256 + threadIdx.x;
    const int stride = gridDim.x * 256;
    for (int i = gid; i < n4; i += stride) {
        const float4 v = ((const float4*)x)[i];
        ushort4 u;
        u.x = f2h(v.x); u.y = f2h(v.y); u.z = f2h(v.z); u.w = f2h(v.w);
        ((ushort4*)xh)[i] = u;
    }
    // weight pack / b5 pad / stats zero / lw,lb pack
    int t = gid;
    bool done = false;
    if (!done && t < 16384) { pack_store(Wp, 128, t / 128, t % 128, w1[t]); done = true; }
    if (!done) { t -= 16384;
        if (t < 8192) { pack_store(Wp + 16384, 64, t / 64, t % 64, w2[t]); done = true; } }
    if (!done) { t -= 8192;
        if (t < 18432) { pack_store(Wp + 24576, 96, t / 96, t % 96, w3[t]); done = true; } }
    if (!done) { t -= 18432;
        if (t < 9216) { pack_store(Wp + 43008, 96, t / 96, t % 96, w4[t]); done = true; } }
    if (!done) { t -= 9216;
        if (t < 1536) {
            const int k = t / 16, c = t % 16;
            pack_store(Wp + 52224, 16, k, c, (c < 10) ? w5[k * 10 + c] : 0.f);
            done = true; } }
    if (!done) { t -= 1536;
        if (t < 16) { b5p[t] = (t < 10) ? b5[t] : 0.f; done = true; } }
    if (!done) { t -= 16;
        if (t < 1280) { sums[t] = 0.f; done = true; } }
    if (!done) { t -= 1280;
        if (t < 64) { lwh[t] = pk2(lw[2 * t], lw[2 * t + 1]); done = true; } }
    if (!done) { t -= 64;
        if (t < 64) { lbh[t] = pk2(lb[2 * t], lb[2 * t + 1]); done = true; } }
    __syncthreads();
    for (int i = threadIdx.x; i < NB; i += 256)
        H[(size_t)i * NBLK + blockIdx.x] = h[i];
}

// ---------------------------------------------------------------------------
// CSR build: radix-style two-pass counting sort by dst, no global atomics.
// ---------------------------------------------------------------------------
__device__ inline int wave_incl_scan(int v, int lane)
{
#pragma unroll
    for (int s = 1; s < 64; s <<= 1) {
        const int t = __shfl_up(v, s, 64);
        if (lane >= s) v += t;
    }
    return v;
}

__global__ __launch_bounds__(1024) void scan1(
    const int* __restrict__ cnt, int* __restrict__ off, int* __restrict__ bsum, int n)
{
    __shared__ int wsum[16];
    const int tid = threadIdx.x, lane = tid & 63, wid = tid >> 6;
    const int i = blockIdx.x * 1024 + tid;
    const int v = (i < n) ? cnt[i] : 0;
    const int incl = wave_incl_scan(v, lane);
    if (lane == 63) wsum[wid] = incl;
    __syncthreads();
    if (wid == 0) {
        int wv = (lane < 16) ? wsum[lane] : 0;
        wv = wave_incl_scan(wv, lane);
        if (lane < 16) wsum[lane] = wv;
    }
    __syncthreads();
    const int excl = (wid > 0 ? wsum[wid - 1] : 0) + incl - v;
    if (i < n) off[i] = excl;
    if (tid == 1023) bsum[blockIdx.x] = wsum[15];
}

// scan3 with scan2 fused: each block serially prefixes the (<=128) block
// totals up to its own blockIdx (thread 0), then adds.
__global__ __launch_bounds__(1024) void scan3f(
    int* __restrict__ off, const int* __restrict__ bsum, int n)
{
    __shared__ int pre;
    if (threadIdx.x == 0) {
        int s = 0;
        for (int j = 0; j < (int)blockIdx.x; ++j) s += bsum[j];
        pre = s;
    }
    __syncthreads();
    const int i = blockIdx.x * 1024 + threadIdx.x;
    if (i < n) off[i] += pre;
}

// deterministic coarse scatter; tmp_e = src|f16(ea)<<16 (final edge payload),
// tmp_d = dst&127 (fine bucket key)
__global__ __launch_bounds__(256) void scatter_coarse(
    const int* __restrict__ src, const int* __restrict__ dst,
    const float* __restrict__ ea, const int* __restrict__ H,
    uint* __restrict__ tmp_e, uchar* __restrict__ tmp_d, int E, int NB, int NBLK)
{
    __shared__ int h[512];
    for (int i = threadIdx.x; i < NB; i += 256)
        h[i] = H[(size_t)i * NBLK + blockIdx.x];
    __syncthreads();
    const int chunk = (E + NBLK - 1) / NBLK;
    const int beg = blockIdx.x * chunk;
    const int end = min(beg + chunk, E);
    for (int i = beg + threadIdx.x; i < end; i += 256) {
        const int d = dst[i];
        const int pos = atomicAdd(&h[d >> 7], 1);
        tmp_e[pos] = (uint)(src[i] & 0xFFFF) | ((uint)f2h(ea[i]) << 16);
        tmp_d[pos] = (uchar)(d & 127);
    }
}

// per-bucket fine scatter; derives per-node off; edges[pos] = tmp_e[i]
__global__ __launch_bounds__(256) void fill_fine2(
    const uint* __restrict__ tmp_e, const uchar* __restrict__ tmp_d,
    const int* __restrict__ H, int* __restrict__ off, uint* __restrict__ edges,
    int N, int E, int NBLK)
{
    __shared__ int cnt[128];
    __shared__ int wtot;
    const int b = blockIdx.x;
    const int base = b * 128;
    const int tid = threadIdx.x;
    const int lo = H[(size_t)b * NBLK];
    const int hi = (b + 1 < (int)gridDim.x) ? H[(size_t)(b + 1) * NBLK] : E;
    if (tid < 128) cnt[tid] = 0;
    __syncthreads();
    for (int i = lo + tid; i < hi; i += 256)
        atomicAdd(&cnt[tmp_d[i]], 1);
    __syncthreads();
    int excl = 0;
    if (tid < 128) {
        const int v = cnt[tid];
        const int incl = wave_incl_scan(v, tid & 63);
        if (tid == 63) wtot = incl;
        excl = incl - v;
    }
    __syncthreads();
    if (tid >= 64 && tid < 128) excl += wtot;
    if (tid < 128) {
        const int o = lo + excl;
        if (base + tid < N) off[base + tid] = o;
        cnt[tid] = o;                         // reuse as heads
    }
    if (b == 0 && tid == 0) off[N] = E;
    __syncthreads();
    for (int i = lo + tid; i < hi; i += 256) {
        const int dl = tmp_d[i];
        const uint pe = tmp_e[i];
        const int pos = atomicAdd(&cnt[dl], 1);
        edges[pos] = pe;
    }
}

// ---------------------------------------------------------------------------
// GINE aggregation (CSR): 16 lanes/node (8 cols/lane, uint4 gather), 4 nodes
// per wave, 1-ahead rotating pipeline (measured-best structure across
// 1-ahead / cond-depth2 / 8-way / uncond-depth2), packed fp16 math, fp16
// accumulators. AFF: BN scale/shift from raw stats, packed to half2.
// outh[node] = fp16( bn(xh[node]) + sum_p relu(bn(xh[src_p]) + a_p*lw + lb) )
// ---------------------------------------------------------------------------
template<bool AFF>
__global__ __launch_bounds__(256) void gine_aggr(
    const ushort* __restrict__ xh, const int* __restrict__ off,
    const uint* __restrict__ edges, const uint* __restrict__ lwh,
    const uint* __restrict__ lbh, const float* __restrict__ su,
    const float* __restrict__ qu, const float* __restrict__ g,
    const float* __restrict__ be, float invN,
    ushort* __restrict__ outh, int N)
{
    const int q = threadIdx.x & 15;                 // cols 8q .. 8q+7
    const int node = blockIdx.x * 16 + (threadIdx.x >> 4);
    if (node >= N) return;
    __half2 lw[4], lb[4], sc[4], sh[4];
#pragma unroll
    for (int i = 0; i < 4; ++i) {
        lw[i] = u2h2(lwh[q * 4 + i]);
        lb[i] = u2h2(lbh[q * 4 + i]);
    }
    if constexpr (AFF) {
        const int c0 = q * 8;
#pragma unroll
        for (int i = 0; i < 4; ++i) {
            const float2 s2 = *(const float2*)(su + c0 + 2 * i);
            const float2 q2 = *(const float2*)(qu + c0 + 2 * i);
            const float2 g2 = *(const float2*)(g + c0 + 2 * i);
            const float2 b2 = *(const float2*)(be + c0 + 2 * i);
            const float m0 = s2.x * invN, m1 = s2.y * invN;
            const float c0f = g2.x * rsqrtf(q2.x * invN - m0 * m0 + BN_EPS);
            const float c1f = g2.y * rsqrtf(q2.y * invN - m1 * m1 + BN_EPS);
            sc[i] = u2h2(pk2(c0f, c1f));
            sh[i] = u2h2(pk2(b2.x - m0 * c0f, b2.y - m1 * c1f));
        }
    }
    __half2 acc[4];
    {
        const uint4 u = ((const uint4*)(xh + (size_t)node * 128))[q];
        acc[0] = u2h2(u.x); acc[1] = u2h2(u.y); acc[2] = u2h2(u.z); acc[3] = u2h2(u.w);
        if constexpr (AFF) {
#pragma unroll
            for (int i = 0; i < 4; ++i) acc[i] = __hfma2(acc[i], sc[i], sh[i]);
        }
    }

    auto proc = [&](uint e, uint4 u) {
        const __half2 a2 = u2h2((e >> 16) * 0x10001u);
        uint ua[4] = {u.x, u.y, u.z, u.w};
#pragma unroll
        for (int i = 0; i < 4; ++i) {
            __half2 x2 = u2h2(ua[i]);
            if constexpr (AFF) x2 = __hfma2(x2, sc[i], sh[i]);
            __half2 m = __hfma2(a2, lw[i], lb[i]);
            m = __hadd2(x2, m);
            m = u2h2(relu2u(h22u(m)));           // packed relu (bit trick)
            acc[i] = __hadd2(acc[i], m);
        }
    };

    int p = off[node];
    const int pend = off[node + 1];
    if (p < pend) {
        uint e = edges[p];
        uint4 u = ((const uint4*)(xh + (size_t)(e & 0xFFFFu) * 128))[q];
        for (++p; p < pend; ++p) {
            const uint en = edges[p];
            const uint4 un = ((const uint4*)(xh + (size_t)(en & 0xFFFFu) * 128))[q];
            proc(e, u);
            e = en; u = un;
        }
        proc(e, u);
    }
    uint4 o;
    o.x = h22u(acc[0]); o.y = h22u(acc[1]); o.z = h22u(acc[2]); o.w = h22u(acc[3]);
    ((uint4*)(outh + (size_t)node * 128))[q] = o;
}

// ---------------------------------------------------------------------------
// MFMA fp16 GEMM + bias + relu + BN-stats epilogue + optional per-k input
// affine. 128 rows/block (each wave: two 16-row groups, W fragment reused).
// Affine scale/shift computed in an LDS prologue from raw stats.
// ---------------------------------------------------------------------------
__device__ __forceinline__ half8 affine_h8(
    half8 a, const float* sc, const float* sh, int k)
{
    const float4 c0 = *(const float4*)(sc + k), c1 = *(const float4*)(sc + k + 4);
    const float4 d0 = *(const float4*)(sh + k), d1 = *(const float4*)(sh + k + 4);
    half8 r;
    r[0] = (_Float16)fmaf((float)a[0], c0.x, d0.x);
    r[1] = (_Float16)fmaf((float)a[1], c0.y, d0.y);
    r[2] = (_Float16)fmaf((float)a[2], c0.z, d0.z);
    r[3] = (_Float16)fmaf((float)a[3], c0.w, d0.w);
    r[4] = (_Float16)fmaf((float)a[4], c1.x, d1.x);
    r[5] = (_Float16)fmaf((float)a[5], c1.y, d1.y);
    r[6] = (_Float16)fmaf((float)a[6], c1.z, d1.z);
    r[7] = (_Float16)fmaf((float)a[7], c1.w, d1.w);
    return r;
}

template<int K, int KS, int M, bool YH, bool AF1, bool AF2>
__global__ __launch_bounds__(256) void gemm_mfma(
    const ushort* __restrict__ A1, const ushort* __restrict__ A2,
    const float* __restrict__ su1, const float* __restrict__ sq1_,
    const float* __restrict__ g1, const float* __restrict__ be1,
    const float* __restrict__ su2, const float* __restrict__ sq2_,
    const float* __restrict__ g2, const float* __restrict__ be2,
    const ushort* __restrict__ Wp, const float* __restrict__ bias,
    void* __restrict__ Yv, float* __restrict__ sum, float* __restrict__ sq,
    int N, float invN)
{
    constexpr int NCT = M / 16;
    constexpr int NKC = K / 32;
    __shared__ float redS[4][M];
    __shared__ float redQ[4][M];
    __shared__ float scL[K];
    __shared__ float shL[K];
    const int tid = threadIdx.x;
    if constexpr (AF1 || AF2) {
        for (int i = tid; i < K; i += 256) {
            float s_, q_, g_, b_;
            if (i < KS) { s_ = su1[i]; q_ = sq1_[i]; g_ = g1[i]; b_ = be1[i]; }
            else        { s_ = su2[i - KS]; q_ = sq2_[i - KS]; g_ = g2[i - KS]; b_ = be2[i - KS]; }
            const float m = s_ * invN;
            const float c = g_ * rsqrtf(q_ * invN - m * m + BN_EPS);
            scL[i] = c; shL[i] = b_ - m * c;
        }
        __syncthreads();
    }
    const int w = tid >> 6, l = tid & 63;
    const int col = l & 15, kg = l >> 4;
    const int rowAa = blockIdx.x * 128 + w * 16 + col;
    const int rowAb = rowAa + 64;
    const int rAa = (rowAa < N) ? rowAa : (N - 1);
    const int rAb = (rowAb < N) ? rowAb : (N - 1);
    f32x4 accA[NCT], accB[NCT];
#pragma unroll
    for (int ct = 0; ct < NCT; ++ct) {
        accA[ct] = f32x4{0.f, 0.f, 0.f, 0.f};
        accB[ct] = f32x4{0.f, 0.f, 0.f, 0.f};
    }
    auto loadA = [&](int rA, int kbase) -> half8 {
        half8 a;
        if constexpr (KS < K) {
            if (kbase >= KS) {
                a = *(const half8*)(A2 + (size_t)rA * (K - KS) + (kbase - KS));
                if constexpr (AF2) a = affine_h8(a, scL, shL, kbase);
            } else {
                a = *(const half8*)(A1 + (size_t)rA * KS + kbase);
                if constexpr (AF1) a = affine_h8(a, scL, shL, kbase);
            }
        } else {
            a = *(const half8*)(A1 + (size_t)rA * K + kbase);
            if constexpr (AF1) a = affine_h8(a, scL, shL, kbase);
        }
        return a;
    };
#pragma unroll
    for (int kc = 0; kc < NKC; ++kc) {
        const int kbase = kc * 32 + kg * 8;
        const half8 aA = loadA(rAa, kbase);
        const half8 aB = loadA(rAb, kbase);
#pragma unroll
        for (int ct = 0; ct < NCT; ++ct) {
            const half8 wf = *(const half8*)(Wp + ((size_t)(kc * NCT + ct) * 64 + l) * 8);
            accA[ct] = __builtin_amdgcn_mfma_f32_16x16x32_f16(aA, wf, accA[ct], 0, 0, 0);
            accB[ct] = __builtin_amdgcn_mfma_f32_16x16x32_f16(aB, wf, accB[ct], 0, 0, 0);
        }
    }
    const int row0a = blockIdx.x * 128 + w * 16 + 4 * kg;
    const int row0b = row0a + 64;
#pragma unroll
    for (int ct = 0; ct < NCT; ++ct) {
        const float bs = bias[ct * 16 + col];
        float sS = 0.f, sQ = 0.f;
#pragma unroll
        for (int r = 0; r < 4; ++r) {
            const int ro = row0a + r;
            if (ro < N) {
                const float o = fmaxf(accA[ct][r] + bs, 0.f);
                if constexpr (YH) ((ushort*)Yv)[(size_t)ro * M + ct * 16 + col] = f2h(o);
                else              ((float*)Yv)[(size_t)ro * M + ct * 16 + col] = o;
                sS += o; sQ = fmaf(o, o, sQ);
            }
        }
#pragma unroll
        for (int r = 0; r < 4; ++r) {
            const int ro = row0b + r;
            if (ro < N) {
                const float o = fmaxf(accB[ct][r] + bs, 0.f);
                if constexpr (YH) ((ushort*)Yv)[(size_t)ro * M + ct * 16 + col] = f2h(o);
                else              ((float*)Yv)[(size_t)ro * M + ct * 16 + col] = o;
                sS += o; sQ = fmaf(o, o, sQ);
            }
        }
        sS += __shfl_xor(sS, 16, 64); sQ += __shfl_xor(sQ, 16, 64);
        sS += __shfl_xor(sS, 32, 64); sQ += __shfl_xor(sQ, 32, 64);
        if (l < 16) { redS[w][ct * 16 + col] = sS; redQ[w][ct * 16 + col] = sQ; }
    }
    __syncthreads();
    for (int i = tid; i < M; i += 256) {
        const float S = redS[0][i] + redS[1][i] + redS[2][i] + redS[3][i];
        const float Q = redQ[0][i] + redQ[1][i] + redQ[2][i] + redQ[3][i];
        unsafeAtomicAdd(&sum[i], S);
        unsafeAtomicAdd(&sq[i], Q);
    }
}

// final BN apply (scale/shift computed inline from raw stats) -> out [N,10]
__global__ __launch_bounds__(256) void bn_apply_final(
    const ushort* __restrict__ Y16h, const float* __restrict__ su,
    const float* __restrict__ qu, const float* __restrict__ g5,
    const float* __restrict__ be5, float* __restrict__ out, int total, float invN)
{
    for (int i = blockIdx.x * 256 + threadIdx.x; i < total; i += gridDim.x * 256) {
        const int n = i / 10;
        const int c = i - n * 10;
        const float m = su[c] * invN;
        const float sc = g5[c] * rsqrtf(qu[c] * invN - m * m + BN_EPS);
        const float sh = be5[c] - m * sc;
        out[i] = fmaf(h2f1(Y16h[(size_t)n * 16 + c]), sc, sh);
    }
}

// ---------------------------------------------------------------------------
extern "C" void kernel_launch(void* const* d_in, const int* in_sizes, int n_in,
                              void* d_out, int out_size, void* d_ws, size_t ws_size,
                              hipStream_t stream)
{
    const float* x   = (const float*)d_in[0];
    const float* ea  = (const float*)d_in[1];
    const int*   ei  = (const int*)d_in[2];
    const float* lw  = (const float*)d_in[3];
    const float* lb  = (const float*)d_in[4];
    const float* w1  = (const float*)d_in[5];
    const float* b1  = (const float*)d_in[6];
    const float* g1  = (const float*)d_in[7];
    const float* be1 = (const float*)d_in[8];
    const float* w2  = (const float*)d_in[9];
    const float* b2  = (const float*)d_in[10];
    const float* g2  = (const float*)d_in[11];
    const float* be2 = (const float*)d_in[12];
    const float* w3  = (const float*)d_in[13];
    const float* b3  = (const float*)d_in[14];
    const float* g3  = (const float*)d_in[15];
    const float* be3 = (const float*)d_in[16];
    const float* w4  = (const float*)d_in[17];
    const float* b4  = (const float*)d_in[18];
    const float* g4  = (const float*)d_in[19];
    const float* be4 = (const float*)d_in[20];
    const float* w5  = (const float*)d_in[21];
    const float* b5  = (const float*)d_in[22];
    const float* g5  = (const float*)d_in[23];
    const float* be5 = (const float*)d_in[24];

    const int N = in_sizes[0] / 128;   // 50000
    const int E = in_sizes[1];         // 1600000
    const int* src = ei;
    const int* dst = ei + E;
    const float invN = 1.0f / (float)N;

    float* ws = (float*)d_ws;
    // fp16 pools (offsets in float units)
    ushort* Pa = (ushort*)ws;                           // N*128 h: xh -> y1h
    ushort* Pb = (ushort*)(ws + (size_t)N * 64);        // N*128 h: t1h -> t2h -> y3h
    ushort* Pc = (ushort*)(ws + (size_t)N * 128);       // N*64 h:  y2h
    ushort* Pd = (ushort*)(ws + (size_t)N * 160);       // N*96 h:  y4h
    ushort* y5h = (ushort*)(ws + (size_t)N * 208);      // N*16 h
    float*  smallr = ws + (size_t)N * 224;
    float*  sums   = smallr;                            // 10 x 128
    float*  b5p    = smallr + 1280;                     // 16
    uint*   lwh    = (uint*)(smallr + 1296);            // 64
    uint*   lbh    = lwh + 64;                          // 64
    ushort* Wp     = (ushort*)(smallr + 1424);          // 53760 halves
    int*    ibase  = (int*)(smallr + 1424 + 26880);
    int*    H      = ibase;                             // NB*NBLK (+pad) = 100160
    int*    bsum   = H + 100160;                        // 128
    uint*   tmp_e  = (uint*)(bsum + 128);               // E uint
    uchar*  tmp_d  = (uchar*)(tmp_e + E);               // E bytes
    uint*   edges  = (uint*)(tmp_d + ((E + 3) & ~3));   // E uint
    int*    off    = (int*)(edges + E);                 // N+1
#define SUM(l)   (sums + (l) * 128)
#define SQ(l)    (sums + (5 + (l)) * 128)

    // ---- CSR build (reused by both convs) + all setup, fused first kernel
    const int NB   = (N + 127) / 128;                   // 391 coarse buckets
    const int NBLK = 256;
    const int nH   = NB * NBLK;                         // 100096
    const int nbH  = (nH + 1023) / 1024;                // 98
    setup_hist<<<NBLK, 256, 0, stream>>>(x, Pa, N * 32, w1, w2, w3, w4, w5, b5,
                                         lw, lb, Wp, b5p, sums, lwh, lbh,
                                         dst, H, E, NB, NBLK);
    scan1<<<nbH, 1024, 0, stream>>>(H, H, bsum, nH);
    scan3f<<<nbH, 1024, 0, stream>>>(H, bsum, nH);
    scatter_coarse<<<NBLK, 256, 0, stream>>>(src, dst, ea, H, tmp_e, tmp_d, E, NB, NBLK);
    fill_fine2<<<NB, 256, 0, stream>>>(tmp_e, tmp_d, H, off, edges, N, E, NBLK);

    const int gemmGrid = (N + 127) / 128;               // 391
    const int aggrGrid = (N + 15) / 16;                 // 3125

    // ---- conv1: t1 = x + sum relu(x[src]+e);  y1 = relu(t1@w1+b1) + stats
    gine_aggr<false><<<aggrGrid, 256, 0, stream>>>(
        Pa, off, edges, lwh, lbh, nullptr, nullptr, nullptr, nullptr, invN, Pb, N);
    gemm_mfma<128, 128, 128, true, false, false><<<gemmGrid, 256, 0, stream>>>(
        Pb, nullptr, nullptr, nullptr, nullptr, nullptr,
        nullptr, nullptr, nullptr, nullptr,
        Wp, b1, Pa, SUM(0), SQ(0), N, invN);                               // y1h -> Pa

    // ---- conv2: t2 = bn(y1) + sum relu(bn(y1)[src]+e)  (affine from stats)
    gine_aggr<true><<<aggrGrid, 256, 0, stream>>>(
        Pa, off, edges, lwh, lbh, SUM(0), SQ(0), g1, be1, invN, Pb, N);    // t2h -> Pb
    gemm_mfma<128, 128, 64, true, false, false><<<gemmGrid, 256, 0, stream>>>(
        Pb, nullptr, nullptr, nullptr, nullptr, nullptr,
        nullptr, nullptr, nullptr, nullptr,
        Wp + 16384, b2, Pc, SUM(1), SQ(1), N, invN);                       // y2h -> Pc

    // ---- lin1: y3 = relu(concat(bn(y1), bn(y2)) @ w3 + b3) (K split 128|64)
    gemm_mfma<192, 128, 96, true, true, true><<<gemmGrid, 256, 0, stream>>>(
        Pa, Pc, SUM(0), SQ(0), g1, be1, SUM(1), SQ(1), g2, be2,
        Wp + 24576, b3, Pb, SUM(2), SQ(2), N, invN);                       // y3h -> Pb

    // ---- mlp1 layer 1: y4 = relu(bn(y3) @ w4 + b4)
    gemm_mfma<96, 96, 96, true, true, false><<<gemmGrid, 256, 0, stream>>>(
        Pb, nullptr, SUM(2), SQ(2), g3, be3, nullptr, nullptr, nullptr, nullptr,
        Wp + 43008, b4, Pd, SUM(3), SQ(3), N, invN);                       // y4h -> Pd

    // ---- mlp1 layer 2: y5 = relu(bn(y4) @ w5p + b5p) [N,16] f16
    gemm_mfma<96, 96, 16, true, true, false><<<gemmGrid, 256, 0, stream>>>(
        Pd, nullptr, SUM(3), SQ(3), g4, be4, nullptr, nullptr, nullptr, nullptr,
        Wp + 52224, b5p, y5h, SUM(4), SQ(4), N, invN);

    // ---- final BN apply -> out [N,10]
    bn_apply_final<<<1024, 256, 0, stream>>>(y5h, SUM(4), SQ(4), g5, be5,
                                             (float*)d_out, N * 10, invN);
#undef SUM
#undef SQ
}